// Round 10
// baseline (405.172 us; speedup 1.0000x reference)
//
#include <hip/hip_runtime.h>
#include <hip/hip_bf16.h>
#include <math.h>

#define N_NODES 100000
#define N_EDGES 1600000
#define F_IN 256
#define H_DIM 128
#define N_GRAPHS 1000

#define NB_BUCKETS ((N_NODES + 255) >> 8)   // 391 buckets of 256 nodes
#define BSTRIDE 392
#define A_BLOCKS 256
#define EPB (N_EDGES / A_BLOCKS)            // 6250 edges per block (exact)

typedef unsigned short bfu;  // bf16 bit pattern
typedef short short8 __attribute__((ext_vector_type(8)));   // 8 bf16 = 4 VGPR
typedef float f32x4 __attribute__((ext_vector_type(4)));    // MFMA accum

__device__ __forceinline__ float b2f(unsigned u) {
    union { unsigned int i; float f; } v;
    v.i = u << 16;
    return v.f;
}
__device__ __forceinline__ bfu f2b(float f) {
    __hip_bfloat16 h = __float2bfloat16(f);  // RNE
    return *reinterpret_cast<bfu*>(&h);
}

// ---------------- CSR build: bucketed counting sort ----------------
__global__ __launch_bounds__(256) void k_hist(const int* __restrict__ dst,
                                              int* __restrict__ cnt_bb) {
    __shared__ int h[BSTRIDE];
    const int t = threadIdx.x;
    for (int i = t; i < BSTRIDE; i += 256) h[i] = 0;
    __syncthreads();
    const int base = blockIdx.x * EPB;
    for (int i = t; i < EPB; i += 256) atomicAdd(&h[dst[base + i] >> 8], 1);
    __syncthreads();
    for (int i = t; i < NB_BUCKETS; i += 256) cnt_bb[blockIdx.x * BSTRIDE + i] = h[i];
}

__global__ __launch_bounds__(256) void k_scan_blocks(int* __restrict__ cnt_bb,
                                                     int* __restrict__ btot) {
    __shared__ int s[256];
    const int t = threadIdx.x;
    const int b = blockIdx.x;
    int v = cnt_bb[t * BSTRIDE + b];
    s[t] = v;
    __syncthreads();
    for (int off = 1; off < 256; off <<= 1) {
        int u = (t >= off) ? s[t - off] : 0;
        __syncthreads();
        s[t] += u;
        __syncthreads();
    }
    cnt_bb[t * BSTRIDE + b] = s[t] - v;
    if (t == 255) btot[b] = s[255];
}

__global__ __launch_bounds__(512) void k_scan_buckets(const int* __restrict__ btot,
                                                      int* __restrict__ bucket_base) {
    __shared__ int s[512];
    const int t = threadIdx.x;
    int v = (t < NB_BUCKETS) ? btot[t] : 0;
    s[t] = v;
    __syncthreads();
    for (int off = 1; off < 512; off <<= 1) {
        int u = (t >= off) ? s[t - off] : 0;
        __syncthreads();
        s[t] += u;
        __syncthreads();
    }
    if (t < NB_BUCKETS) bucket_base[t] = s[t] - v;
    if (t == 0) bucket_base[NB_BUCKETS] = N_EDGES;
}

__global__ __launch_bounds__(256) void k_stage(const int* __restrict__ src,
                                               const int* __restrict__ dst,
                                               const int* __restrict__ cnt_bb,
                                               const int* __restrict__ bucket_base,
                                               unsigned* __restrict__ staging) {
    __shared__ int cur[BSTRIDE];
    const int t = threadIdx.x;
    const int blk = blockIdx.x;
    for (int i = t; i < NB_BUCKETS; i += 256)
        cur[i] = bucket_base[i] + cnt_bb[blk * BSTRIDE + i];
    __syncthreads();
    const int base = blk * EPB;
    for (int i = t; i < EPB; i += 256) {
        int d = dst[base + i];
        int s = src[base + i];
        int b = d >> 8;
        int pos = atomicAdd(&cur[b], 1);
        staging[pos] = (unsigned)s | ((unsigned)(d & 255) << 24);
    }
}

__global__ __launch_bounds__(256) void k_bucket(const unsigned* __restrict__ staging,
                                                const int* __restrict__ bucket_base,
                                                int* __restrict__ row_ptr,
                                                float* __restrict__ dis,
                                                int* __restrict__ col) {
    __shared__ int h[256];
    __shared__ int sc[256];
    __shared__ int cur[256];
    const int t = threadIdx.x;
    const int b = blockIdx.x;
    const int s0 = bucket_base[b];
    const int ne = bucket_base[b + 1] - s0;
    h[t] = 0;
    __syncthreads();
    for (int i = t; i < ne; i += 256) atomicAdd(&h[staging[s0 + i] >> 24], 1);
    __syncthreads();
    int myc = h[t];
    sc[t] = myc;
    __syncthreads();
    for (int off = 1; off < 256; off <<= 1) {
        int u = (t >= off) ? sc[t - off] : 0;
        __syncthreads();
        sc[t] += u;
        __syncthreads();
    }
    int excl = sc[t] - myc;
    int node = b * 256 + t;
    if (node <= N_NODES) row_ptr[node] = s0 + excl;
    if (node < N_NODES) dis[node] = rsqrtf((float)(myc + 1));
    cur[t] = s0 + excl;
    __syncthreads();
    for (int i = t; i < ne; i += 256) {
        unsigned u = staging[s0 + i];
        int pos = atomicAdd(&cur[u >> 24], 1);
        col[pos] = (int)(u & 0xFFFFFFu);
    }
}

// ---------------- merged: W pre-packs + graph bounds (one launch) ----------------
__device__ __forceinline__ void wpack_one(const float* __restrict__ W,
                                          bfu* __restrict__ Wp, int u) {
    int lane = u & 63;
    int nf = (u >> 6) & 7;
    int ks = u >> 9;
    int k = ks * 32 + (lane >> 4) * 8;
    int n = nf * 16 + (lane & 15);
    bfu o[8];
#pragma unroll
    for (int j = 0; j < 8; ++j) o[j] = f2b(W[(k + j) * 128 + n]);
    uint4 pk;
    pk.x = (unsigned)o[0] | ((unsigned)o[1] << 16);
    pk.y = (unsigned)o[2] | ((unsigned)o[3] << 16);
    pk.z = (unsigned)o[4] | ((unsigned)o[5] << 16);
    pk.w = (unsigned)o[6] | ((unsigned)o[7] << 16);
    *(uint4*)&Wp[u * 8] = pk;
}

__global__ __launch_bounds__(256) void k_misc(const float* __restrict__ W1,
                                              const float* __restrict__ W2,
                                              const float* __restrict__ W3,
                                              bfu* __restrict__ wp1, bfu* __restrict__ wp2,
                                              bfu* __restrict__ wp3,
                                              const int* __restrict__ batch,
                                              int* __restrict__ bounds) {
    const int b = blockIdx.x, t = threadIdx.x;
    if (b < 16) {
        wpack_one(W1, wp1, b * 256 + t);          // K=256: 4096 items
    } else if (b < 24) {
        wpack_one(W2, wp2, (b - 16) * 256 + t);   // K=128: 2048 items
    } else if (b < 32) {
        wpack_one(W3, wp3, (b - 24) * 256 + t);
    } else {
        int g = (b - 32) * 256 + t;
        if (g <= N_GRAPHS) {
            int lo = 0, hi = N_NODES;
            while (lo < hi) {
                int mid = (lo + hi) >> 1;
                if (batch[mid] < g) lo = mid + 1; else hi = mid;
            }
            bounds[g] = lo;
        }
    }
}

// ---------------- mm1 v3: direct-to-register fragments, no LDS, no barriers ----------------
// 256 thr = 4 waves x 16 rows; all 16 A-loads (fp32) issued up-front; cvt->bf16 in regs.
__global__ __launch_bounds__(256, 4) void k_mm1(const float* __restrict__ A,
                                                const bfu* __restrict__ Wp,
                                                const float* __restrict__ dis,
                                                bfu* __restrict__ C, int M) {
    const int t = threadIdx.x;
    const int w = t >> 6, l = t & 63, l15 = l & 15, lhi = l >> 4;
    const int row = blockIdx.x * 64 + w * 16 + l15;
    const int rowc = row < M ? row : M - 1;   // clamp: no OOB, garbage rows never stored
    const float* ap = A + (long)rowc * 256 + lhi * 8;

    float4 va[8][2];
#pragma unroll
    for (int ks = 0; ks < 8; ++ks) {
        va[ks][0] = *(const float4*)(ap + ks * 32);
        va[ks][1] = *(const float4*)(ap + ks * 32 + 4);
    }

    f32x4 acc[8];
#pragma unroll
    for (int nf = 0; nf < 8; ++nf) acc[nf] = (f32x4)0.0f;

#pragma unroll
    for (int ks = 0; ks < 8; ++ks) {
        unsigned p0 = (unsigned)f2b(va[ks][0].x) | ((unsigned)f2b(va[ks][0].y) << 16);
        unsigned p1 = (unsigned)f2b(va[ks][0].z) | ((unsigned)f2b(va[ks][0].w) << 16);
        unsigned p2 = (unsigned)f2b(va[ks][1].x) | ((unsigned)f2b(va[ks][1].y) << 16);
        unsigned p3 = (unsigned)f2b(va[ks][1].z) | ((unsigned)f2b(va[ks][1].w) << 16);
        uint4 afu = make_uint4(p0, p1, p2, p3);
        short8 af = *(short8*)&afu;
        const bfu* wp = Wp + ((long)(ks * 8) * 64 + l) * 8;
#pragma unroll
        for (int nf = 0; nf < 8; ++nf) {
            short8 wf = *(const short8*)(wp + (long)nf * 64 * 8);
            acc[nf] = __builtin_amdgcn_mfma_f32_16x16x32_bf16(wf, af, acc[nf], 0, 0, 0);
        }
    }
    if (row < M) {
        float sc = dis[row];
        int nb0 = lhi * 4;
#pragma unroll
        for (int nf = 0; nf < 8; ++nf) {
            uint2 pk;
            pk.x = (unsigned)f2b(acc[nf][0] * sc) | ((unsigned)f2b(acc[nf][1] * sc) << 16);
            pk.y = (unsigned)f2b(acc[nf][2] * sc) | ((unsigned)f2b(acc[nf][3] * sc) << 16);
            *(uint2*)&C[(long)row * 128 + nf * 16 + nb0] = pk;
        }
    }
}

// ---------------- gather helpers ----------------
__device__ __forceinline__ void acc8v(float* a, uint4 v) {
    a[0] += b2f(v.x & 0xffff); a[1] += b2f(v.x >> 16);
    a[2] += b2f(v.y & 0xffff); a[3] += b2f(v.y >> 16);
    a[4] += b2f(v.z & 0xffff); a[5] += b2f(v.z >> 16);
    a[6] += b2f(v.w & 0xffff); a[7] += b2f(v.w >> 16);
}

// ---------------- FUSED agg+mm v2: 512 thr, 128 nodes/block ----------------
// gather: 4 lanes/node, 32 ch/lane, 2-edge batched loads; MFMA: 8 waves x 16 rows.
template <int KNEXT>
__global__ __launch_bounds__(512) void k_agg_mm(const int* __restrict__ row_ptr,
                                                const int* __restrict__ col,
                                                const float* __restrict__ dis,
                                                const bfu* __restrict__ tprev,
                                                const float* __restrict__ bvec,
                                                const bfu* __restrict__ Wp,
                                                bfu* __restrict__ tnext, int M) {
    __shared__ bfu Hs[128 * 136];  // 128 rows x 128 bf16, pitch 272 B
    const int t = threadIdx.x;
    const int nrow = t >> 2;                  // 0..127
    const int node = blockIdx.x * 128 + nrow;
    const int lz = t & 3;
    const int ch = lz * 32;

    if (node < M) {
        float a[32];
#pragma unroll
        for (int j = 0; j < 32; ++j) a[j] = 0.0f;
        const bfu* tp = tprev + ch;
        // self term
        {
            const bfu* r = tp + (long)node * 128;
#pragma unroll
            for (int q = 0; q < 4; ++q) acc8v(a + q * 8, *(const uint4*)(r + q * 8));
        }
        int e = row_ptr[node];
        const int end = row_ptr[node + 1];
        for (; e + 1 < end; e += 2) {
            int s0 = col[e], s1 = col[e + 1];
            uint4 v[2][4];
            const bfu* r0 = tp + (long)s0 * 128;
            const bfu* r1 = tp + (long)s1 * 128;
#pragma unroll
            for (int q = 0; q < 4; ++q) v[0][q] = *(const uint4*)(r0 + q * 8);
#pragma unroll
            for (int q = 0; q < 4; ++q) v[1][q] = *(const uint4*)(r1 + q * 8);
#pragma unroll
            for (int q = 0; q < 4; ++q) acc8v(a + q * 8, v[0][q]);
#pragma unroll
            for (int q = 0; q < 4; ++q) acc8v(a + q * 8, v[1][q]);
        }
        if (e < end) {
            const bfu* r = tp + (long)col[e] * 128;
#pragma unroll
            for (int q = 0; q < 4; ++q) acc8v(a + q * 8, *(const uint4*)(r + q * 8));
        }
        const float dn = dis[node];
        uint pk[16];
#pragma unroll
        for (int j = 0; j < 16; ++j) {
            float lo = fmaxf(a[2 * j] * dn + bvec[ch + 2 * j], 0.0f);
            float hi = fmaxf(a[2 * j + 1] * dn + bvec[ch + 2 * j + 1], 0.0f);
            pk[j] = (unsigned)f2b(lo) | ((unsigned)f2b(hi) << 16);
        }
        bfu* hrow = &Hs[nrow * 136 + ch];
#pragma unroll
        for (int q = 0; q < 4; ++q)
            *(uint4*)(hrow + q * 8) = make_uint4(pk[4 * q], pk[4 * q + 1], pk[4 * q + 2], pk[4 * q + 3]);
    }
    __syncthreads();
    // ---- MFMA from LDS: 8 waves x 16 rows ----
    const int w = t >> 6, l = t & 63, l15 = l & 15, lhi = l >> 4;
    f32x4 acc[8];
#pragma unroll
    for (int nf = 0; nf < 8; ++nf) acc[nf] = (f32x4)0.0f;
    constexpr int KS = KNEXT / 32;
#pragma unroll
    for (int ks = 0; ks < KS; ++ks) {
        short8 af = *(const short8*)&Hs[(w * 16 + l15) * 136 + ks * 32 + lhi * 8];
        const bfu* wp = Wp + ((long)(ks * 8) * 64 + l) * 8;
#pragma unroll
        for (int nf = 0; nf < 8; ++nf) {
            short8 wf = *(const short8*)(wp + (long)nf * 64 * 8);
            acc[nf] = __builtin_amdgcn_mfma_f32_16x16x32_bf16(wf, af, acc[nf], 0, 0, 0);
        }
    }
    int row = blockIdx.x * 128 + w * 16 + l15;
    if (row < M) {
        float sc = dis[row];
        int nb0 = lhi * 4;
#pragma unroll
        for (int nf = 0; nf < 8; ++nf) {
            uint2 pko;
            pko.x = (unsigned)f2b(acc[nf][0] * sc) | ((unsigned)f2b(acc[nf][1] * sc) << 16);
            pko.y = (unsigned)f2b(acc[nf][2] * sc) | ((unsigned)f2b(acc[nf][3] * sc) << 16);
            *(uint2*)&tnext[(long)row * 128 + nf * 16 + nb0] = pko;
        }
    }
}

// ---------------- standalone CSR gather agg (layer 3; R6-proven form) ----------------
__global__ __launch_bounds__(256) void k_agg(const int* __restrict__ row_ptr,
                                             const int* __restrict__ col,
                                             const float* __restrict__ dis,
                                             const bfu* __restrict__ tbuf,
                                             const float* __restrict__ b,
                                             bfu* __restrict__ h) {
    const int t = threadIdx.x;
    const int node = blockIdx.x * 8 + (t >> 5);
    const int lane = t & 31;
    if (node >= N_NODES) return;
    const int q = lane << 2;

    uint2 sv = *(const uint2*)&tbuf[(long)node * 128 + q];
    float a0 = b2f(sv.x & 0xffff);
    float a1 = b2f(sv.x >> 16);
    float a2 = b2f(sv.y & 0xffff);
    float a3 = b2f(sv.y >> 16);

    int e = row_ptr[node];
    const int end = row_ptr[node + 1];
    for (; e + 3 < end; e += 4) {
        int s0 = col[e], s1 = col[e + 1], s2 = col[e + 2], s3 = col[e + 3];
        uint2 v0 = *(const uint2*)&tbuf[(long)s0 * 128 + q];
        uint2 v1 = *(const uint2*)&tbuf[(long)s1 * 128 + q];
        uint2 v2 = *(const uint2*)&tbuf[(long)s2 * 128 + q];
        uint2 v3 = *(const uint2*)&tbuf[(long)s3 * 128 + q];
        a0 += (b2f(v0.x & 0xffff) + b2f(v1.x & 0xffff)) +
              (b2f(v2.x & 0xffff) + b2f(v3.x & 0xffff));
        a1 += (b2f(v0.x >> 16) + b2f(v1.x >> 16)) +
              (b2f(v2.x >> 16) + b2f(v3.x >> 16));
        a2 += (b2f(v0.y & 0xffff) + b2f(v1.y & 0xffff)) +
              (b2f(v2.y & 0xffff) + b2f(v3.y & 0xffff));
        a3 += (b2f(v0.y >> 16) + b2f(v1.y >> 16)) +
              (b2f(v2.y >> 16) + b2f(v3.y >> 16));
    }
    for (; e < end; ++e) {
        int s0 = col[e];
        uint2 v0 = *(const uint2*)&tbuf[(long)s0 * 128 + q];
        a0 += b2f(v0.x & 0xffff);
        a1 += b2f(v0.x >> 16);
        a2 += b2f(v0.y & 0xffff);
        a3 += b2f(v0.y >> 16);
    }
    const float dn = dis[node];
    float4 bb = *(const float4*)&b[q];
    float o0 = fmaxf(a0 * dn + bb.x, 0.0f);
    float o1 = fmaxf(a1 * dn + bb.y, 0.0f);
    float o2 = fmaxf(a2 * dn + bb.z, 0.0f);
    float o3 = fmaxf(a3 * dn + bb.w, 0.0f);
    uint2 pk;
    pk.x = (unsigned)f2b(o0) | ((unsigned)f2b(o1) << 16);
    pk.y = (unsigned)f2b(o2) | ((unsigned)f2b(o3) << 16);
    *(uint2*)&h[(long)node * 128 + q] = pk;
}

// ---------------- fused pool (mean over segment; h already relu'd) + MLP head ----------------
__global__ __launch_bounds__(128) void k_pool_head(const int* __restrict__ bounds,
                                                   const bfu* __restrict__ h,
                                                   const float* __restrict__ fw1, const float* __restrict__ fb1,
                                                   const float* __restrict__ fw2, const float* __restrict__ fb2,
                                                   float* __restrict__ out) {
    const int g = blockIdx.x;
    const int t = threadIdx.x;
    const int s = bounds[g], e = bounds[g + 1];
    float sum = 0.0f;
    int n = s;
    for (; n + 1 < e; n += 2) {
        sum += b2f(h[(long)n * 128 + t]);
        sum += b2f(h[(long)(n + 1) * 128 + t]);
    }
    if (n < e) sum += b2f(h[(long)n * 128 + t]);

    __shared__ float sg[128];
    __shared__ float sh[32];
    float inv = 1.0f / fmaxf((float)(e - s), 1.0f);
    sg[t] = sum * inv;
    __syncthreads();
    if (t < 32) {
        float a = fb1[t];
#pragma unroll 8
        for (int k = 0; k < 128; ++k) a += sg[k] * fw1[k * 32 + t];
        sh[t] = fmaxf(a, 0.0f);
    }
    __syncthreads();
    if (t == 0) {
        float l0 = fb2[0], l1 = fb2[1];
        for (int k = 0; k < 32; ++k) {
            l0 += sh[k] * fw2[k * 2];
            l1 += sh[k] * fw2[k * 2 + 1];
        }
        float m = fmaxf(l0, l1);
        float lse = m + logf(expf(l0 - m) + expf(l1 - m));
        out[g * 2 + 0] = l0 - lse;
        out[g * 2 + 1] = l1 - lse;
    }
}

extern "C" void kernel_launch(void* const* d_in, const int* in_sizes, int n_in,
                              void* d_out, int out_size, void* d_ws, size_t ws_size,
                              hipStream_t stream) {
    const float* x  = (const float*)d_in[0];
    const int* ei   = (const int*)d_in[1];
    const int* batch = (const int*)d_in[2];
    const float* W1 = (const float*)d_in[3];
    const float* b1 = (const float*)d_in[4];
    const float* W2 = (const float*)d_in[5];
    const float* b2 = (const float*)d_in[6];
    const float* W3 = (const float*)d_in[7];
    const float* b3 = (const float*)d_in[8];
    const float* fw1 = (const float*)d_in[9];
    const float* fb1 = (const float*)d_in[10];
    const float* fw2 = (const float*)d_in[11];
    const float* fb2 = (const float*)d_in[12];
    float* out = (float*)d_out;

    const int* src = ei;
    const int* dst = ei + N_EDGES;

    // workspace layout (all chunks multiple of 16 B)
    char* ws = (char*)d_ws;
    int*      cnt_bb      = (int*)ws;                            // 256*392
    int*      btot        = cnt_bb + A_BLOCKS * BSTRIDE;         // 392
    int*      bucket_base = btot + BSTRIDE;                      // 392+8
    unsigned* staging     = (unsigned*)(bucket_base + BSTRIDE + 8);  // E
    int*      row_ptr     = (int*)(staging + N_EDGES);           // N+4
    float*    dis         = (float*)(row_ptr + N_NODES + 4);     // N
    int*      col         = (int*)(dis + N_NODES);               // E
    int*      bounds      = col + N_EDGES;                       // G+1 (+pad)
    bfu*      wpack1      = (bfu*)(bounds + N_GRAPHS + 8);       // 32768 bfu (K=256)
    bfu*      wpack2      = wpack1 + 32768;                      // 16384 bfu (K=128)
    bfu*      wpack3      = wpack2 + 16384;                      // 16384 bfu
    bfu*      buf0        = wpack3 + 16384;                      // N*128 bf16
    bfu*      buf1        = buf0 + (long)N_NODES * 128;          // N*128 bf16

    // ---- CSR build (counting sort) + merged wpack/bounds ----
    k_hist<<<A_BLOCKS, 256, 0, stream>>>(dst, cnt_bb);
    k_scan_blocks<<<NB_BUCKETS, 256, 0, stream>>>(cnt_bb, btot);
    k_scan_buckets<<<1, 512, 0, stream>>>(btot, bucket_base);
    k_stage<<<A_BLOCKS, 256, 0, stream>>>(src, dst, cnt_bb, bucket_base, staging);
    k_bucket<<<NB_BUCKETS, 256, 0, stream>>>(staging, bucket_base, row_ptr, dis, col);
    k_misc<<<36, 256, 0, stream>>>(W1, W2, W3, wpack1, wpack2, wpack3, batch, bounds);

    const int mm1Grid = (N_NODES + 63) / 64;       // 1563
    const int fusedGrid = (N_NODES + 127) / 128;   // 782
    const int aggGrid = (N_NODES + 7) / 8;         // 12500

    // layer 1: t1 = (x @ W1) * dis  (direct-to-register MFMA)
    k_mm1<<<mm1Grid, 256, 0, stream>>>(x, wpack1, dis, buf0, N_NODES);
    // fused layer1-agg + layer2-mm
    k_agg_mm<H_DIM><<<fusedGrid, 512, 0, stream>>>(row_ptr, col, dis, buf0, b1, wpack2, buf1, N_NODES);
    // fused layer2-agg + layer3-mm
    k_agg_mm<H_DIM><<<fusedGrid, 512, 0, stream>>>(row_ptr, col, dis, buf1, b2, wpack3, buf0, N_NODES);
    // layer3 agg
    k_agg<<<aggGrid, 256, 0, stream>>>(row_ptr, col, dis, buf0, b3, buf1);

    // fused pool + head
    k_pool_head<<<N_GRAPHS, 128, 0, stream>>>(bounds, buf1, fw1, fb1, fw2, fb2, out);
}

// Round 11
// 338.036 us; speedup vs baseline: 1.1986x; 1.1986x over previous
//
#include <hip/hip_runtime.h>
#include <hip/hip_bf16.h>
#include <math.h>

#define N_NODES 100000
#define N_EDGES 1600000
#define F_IN 256
#define H_DIM 128
#define N_GRAPHS 1000

#define NB_BUCKETS ((N_NODES + 255) >> 8)   // 391 buckets of 256 nodes
#define BSTRIDE 392
#define A_BLOCKS 256
#define EPB (N_EDGES / A_BLOCKS)            // 6250 edges per block (exact)

typedef unsigned short bfu;  // bf16 bit pattern
typedef unsigned char u8;
typedef short short8 __attribute__((ext_vector_type(8)));   // 8 bf16 = 4 VGPR
typedef float f32x4 __attribute__((ext_vector_type(4)));    // MFMA accum
typedef float f32x2 __attribute__((ext_vector_type(2)));

__device__ __forceinline__ float b2f(unsigned u) {
    union { unsigned int i; float f; } v;
    v.i = u << 16;
    return v.f;
}
__device__ __forceinline__ bfu f2b(float f) {
    __hip_bfloat16 h = __float2bfloat16(f);  // RNE
    return *reinterpret_cast<bfu*>(&h);
}
// 4 f32 -> 4 fp8(e4m3) bytes packed in a dword (HW cvt, RNE+sat)
__device__ __forceinline__ unsigned pk4_fp8(float v0, float v1, float v2, float v3) {
    int r = __builtin_amdgcn_cvt_pk_fp8_f32(v0, v1, 0, false);
    r = __builtin_amdgcn_cvt_pk_fp8_f32(v2, v3, r, true);
    return (unsigned)r;
}
// accumulate 16 fp8 (one uint4) into a[0..15]
__device__ __forceinline__ void acc16_fp8(float* a, uint4 v) {
    f32x2 p;
    p = __builtin_amdgcn_cvt_pk_f32_fp8((int)v.x, false); a[0] += p.x;  a[1] += p.y;
    p = __builtin_amdgcn_cvt_pk_f32_fp8((int)v.x, true);  a[2] += p.x;  a[3] += p.y;
    p = __builtin_amdgcn_cvt_pk_f32_fp8((int)v.y, false); a[4] += p.x;  a[5] += p.y;
    p = __builtin_amdgcn_cvt_pk_f32_fp8((int)v.y, true);  a[6] += p.x;  a[7] += p.y;
    p = __builtin_amdgcn_cvt_pk_f32_fp8((int)v.z, false); a[8] += p.x;  a[9] += p.y;
    p = __builtin_amdgcn_cvt_pk_f32_fp8((int)v.z, true);  a[10] += p.x; a[11] += p.y;
    p = __builtin_amdgcn_cvt_pk_f32_fp8((int)v.w, false); a[12] += p.x; a[13] += p.y;
    p = __builtin_amdgcn_cvt_pk_f32_fp8((int)v.w, true);  a[14] += p.x; a[15] += p.y;
}

// ---------------- CSR build: bucketed counting sort ----------------
__global__ __launch_bounds__(256) void k_hist(const int* __restrict__ dst,
                                              int* __restrict__ cnt_bb) {
    __shared__ int h[BSTRIDE];
    const int t = threadIdx.x;
    for (int i = t; i < BSTRIDE; i += 256) h[i] = 0;
    __syncthreads();
    const int base = blockIdx.x * EPB;
    for (int i = t; i < EPB; i += 256) atomicAdd(&h[dst[base + i] >> 8], 1);
    __syncthreads();
    for (int i = t; i < NB_BUCKETS; i += 256) cnt_bb[blockIdx.x * BSTRIDE + i] = h[i];
}

__global__ __launch_bounds__(256) void k_scan_blocks(int* __restrict__ cnt_bb,
                                                     int* __restrict__ btot) {
    __shared__ int s[256];
    const int t = threadIdx.x;
    const int b = blockIdx.x;
    int v = cnt_bb[t * BSTRIDE + b];
    s[t] = v;
    __syncthreads();
    for (int off = 1; off < 256; off <<= 1) {
        int u = (t >= off) ? s[t - off] : 0;
        __syncthreads();
        s[t] += u;
        __syncthreads();
    }
    cnt_bb[t * BSTRIDE + b] = s[t] - v;
    if (t == 255) btot[b] = s[255];
}

__global__ __launch_bounds__(512) void k_scan_buckets(const int* __restrict__ btot,
                                                      int* __restrict__ bucket_base) {
    __shared__ int s[512];
    const int t = threadIdx.x;
    int v = (t < NB_BUCKETS) ? btot[t] : 0;
    s[t] = v;
    __syncthreads();
    for (int off = 1; off < 512; off <<= 1) {
        int u = (t >= off) ? s[t - off] : 0;
        __syncthreads();
        s[t] += u;
        __syncthreads();
    }
    if (t < NB_BUCKETS) bucket_base[t] = s[t] - v;
    if (t == 0) bucket_base[NB_BUCKETS] = N_EDGES;
}

__global__ __launch_bounds__(256) void k_stage(const int* __restrict__ src,
                                               const int* __restrict__ dst,
                                               const int* __restrict__ cnt_bb,
                                               const int* __restrict__ bucket_base,
                                               unsigned* __restrict__ staging) {
    __shared__ int cur[BSTRIDE];
    const int t = threadIdx.x;
    const int blk = blockIdx.x;
    for (int i = t; i < NB_BUCKETS; i += 256)
        cur[i] = bucket_base[i] + cnt_bb[blk * BSTRIDE + i];
    __syncthreads();
    const int base = blk * EPB;
    for (int i = t; i < EPB; i += 256) {
        int d = dst[base + i];
        int s = src[base + i];
        int b = d >> 8;
        int pos = atomicAdd(&cur[b], 1);
        staging[pos] = (unsigned)s | ((unsigned)(d & 255) << 24);
    }
}

__global__ __launch_bounds__(256) void k_bucket(const unsigned* __restrict__ staging,
                                                const int* __restrict__ bucket_base,
                                                int* __restrict__ row_ptr,
                                                float* __restrict__ dis,
                                                int* __restrict__ col) {
    __shared__ int h[256];
    __shared__ int sc[256];
    __shared__ int cur[256];
    const int t = threadIdx.x;
    const int b = blockIdx.x;
    const int s0 = bucket_base[b];
    const int ne = bucket_base[b + 1] - s0;
    h[t] = 0;
    __syncthreads();
    for (int i = t; i < ne; i += 256) atomicAdd(&h[staging[s0 + i] >> 24], 1);
    __syncthreads();
    int myc = h[t];
    sc[t] = myc;
    __syncthreads();
    for (int off = 1; off < 256; off <<= 1) {
        int u = (t >= off) ? sc[t - off] : 0;
        __syncthreads();
        sc[t] += u;
        __syncthreads();
    }
    int excl = sc[t] - myc;
    int node = b * 256 + t;
    if (node <= N_NODES) row_ptr[node] = s0 + excl;
    if (node < N_NODES) dis[node] = rsqrtf((float)(myc + 1));
    cur[t] = s0 + excl;
    __syncthreads();
    for (int i = t; i < ne; i += 256) {
        unsigned u = staging[s0 + i];
        int pos = atomicAdd(&cur[u >> 24], 1);
        col[pos] = (int)(u & 0xFFFFFFu);
    }
}

// ---------------- merged: W pre-packs + graph bounds (one launch) ----------------
__device__ __forceinline__ void wpack_one(const float* __restrict__ W,
                                          bfu* __restrict__ Wp, int u) {
    int lane = u & 63;
    int nf = (u >> 6) & 7;
    int ks = u >> 9;
    int k = ks * 32 + (lane >> 4) * 8;
    int n = nf * 16 + (lane & 15);
    bfu o[8];
#pragma unroll
    for (int j = 0; j < 8; ++j) o[j] = f2b(W[(k + j) * 128 + n]);
    uint4 pk;
    pk.x = (unsigned)o[0] | ((unsigned)o[1] << 16);
    pk.y = (unsigned)o[2] | ((unsigned)o[3] << 16);
    pk.z = (unsigned)o[4] | ((unsigned)o[5] << 16);
    pk.w = (unsigned)o[6] | ((unsigned)o[7] << 16);
    *(uint4*)&Wp[u * 8] = pk;
}

__global__ __launch_bounds__(256) void k_misc(const float* __restrict__ W1,
                                              const float* __restrict__ W2,
                                              const float* __restrict__ W3,
                                              bfu* __restrict__ wp1, bfu* __restrict__ wp2,
                                              bfu* __restrict__ wp3,
                                              const int* __restrict__ batch,
                                              int* __restrict__ bounds) {
    const int b = blockIdx.x, t = threadIdx.x;
    if (b < 16) {
        wpack_one(W1, wp1, b * 256 + t);
    } else if (b < 24) {
        wpack_one(W2, wp2, (b - 16) * 256 + t);
    } else if (b < 32) {
        wpack_one(W3, wp3, (b - 24) * 256 + t);
    } else {
        int g = (b - 32) * 256 + t;
        if (g <= N_GRAPHS) {
            int lo = 0, hi = N_NODES;
            while (lo < hi) {
                int mid = (lo + hi) >> 1;
                if (batch[mid] < g) lo = mid + 1; else hi = mid;
            }
            bounds[g] = lo;
        }
    }
}

// ---------------- mm1: direct-to-register fragments; OUT = fp8 t1 ----------------
__global__ __launch_bounds__(256, 4) void k_mm1(const float* __restrict__ A,
                                                const bfu* __restrict__ Wp,
                                                const float* __restrict__ dis,
                                                u8* __restrict__ C8, int M) {
    const int t = threadIdx.x;
    const int w = t >> 6, l = t & 63, l15 = l & 15, lhi = l >> 4;
    const int row = blockIdx.x * 64 + w * 16 + l15;
    const int rowc = row < M ? row : M - 1;
    const float* ap = A + (long)rowc * 256 + lhi * 8;

    float4 va[8][2];
#pragma unroll
    for (int ks = 0; ks < 8; ++ks) {
        va[ks][0] = *(const float4*)(ap + ks * 32);
        va[ks][1] = *(const float4*)(ap + ks * 32 + 4);
    }

    f32x4 acc[8];
#pragma unroll
    for (int nf = 0; nf < 8; ++nf) acc[nf] = (f32x4)0.0f;

#pragma unroll
    for (int ks = 0; ks < 8; ++ks) {
        unsigned p0 = (unsigned)f2b(va[ks][0].x) | ((unsigned)f2b(va[ks][0].y) << 16);
        unsigned p1 = (unsigned)f2b(va[ks][0].z) | ((unsigned)f2b(va[ks][0].w) << 16);
        unsigned p2 = (unsigned)f2b(va[ks][1].x) | ((unsigned)f2b(va[ks][1].y) << 16);
        unsigned p3 = (unsigned)f2b(va[ks][1].z) | ((unsigned)f2b(va[ks][1].w) << 16);
        uint4 afu = make_uint4(p0, p1, p2, p3);
        short8 af = *(short8*)&afu;
        const bfu* wp = Wp + ((long)(ks * 8) * 64 + l) * 8;
#pragma unroll
        for (int nf = 0; nf < 8; ++nf) {
            short8 wf = *(const short8*)(wp + (long)nf * 64 * 8);
            acc[nf] = __builtin_amdgcn_mfma_f32_16x16x32_bf16(wf, af, acc[nf], 0, 0, 0);
        }
    }
    if (row < M) {
        float sc = dis[row];
        int nb0 = lhi * 4;
#pragma unroll
        for (int nf = 0; nf < 8; ++nf) {
            unsigned pk = pk4_fp8(acc[nf][0] * sc, acc[nf][1] * sc,
                                  acc[nf][2] * sc, acc[nf][3] * sc);
            *(unsigned*)&C8[(long)row * 128 + nf * 16 + nb0] = pk;
        }
    }
}

// ---------------- FUSED agg+mm (R9 shape): fp8 gather -> bf16 LDS -> MFMA ----------------
// 256 thr; 64 dst nodes/block; 4 lanes/node x 32ch; OUT_BF16 selects t-next storage type.
template <bool OUT_BF16>
__global__ __launch_bounds__(256) void k_agg_mm(const int* __restrict__ row_ptr,
                                                const int* __restrict__ col,
                                                const float* __restrict__ dis,
                                                const u8* __restrict__ tprev8,
                                                const float* __restrict__ bvec,
                                                const bfu* __restrict__ Wp,
                                                bfu* __restrict__ tnext16,
                                                u8* __restrict__ tnext8, int M) {
    __shared__ bfu Hs[64 * 136];  // 64 rows x 128 bf16, pitch 272 B
    const int t = threadIdx.x;
    const int nrow = t >> 2;                 // 0..63
    const int node = blockIdx.x * 64 + nrow;
    const int lz = t & 3;
    const int ch = lz * 32;                  // this lane's 32 channels (32 fp8 bytes)

    if (node < M) {
        float a[32];
#pragma unroll
        for (int j = 0; j < 32; ++j) a[j] = 0.0f;
        const u8* tp = tprev8 + ch;
        // self term
        {
            const u8* r = tp + (long)node * 128;
            acc16_fp8(a, *(const uint4*)r);
            acc16_fp8(a + 16, *(const uint4*)(r + 16));
        }
        int e = row_ptr[node];
        const int end = row_ptr[node + 1];
        for (; e + 1 < end; e += 2) {
            int s0 = col[e], s1 = col[e + 1];
            const u8* r0 = tp + (long)s0 * 128;
            const u8* r1 = tp + (long)s1 * 128;
            uint4 v00 = *(const uint4*)r0;
            uint4 v01 = *(const uint4*)(r0 + 16);
            uint4 v10 = *(const uint4*)r1;
            uint4 v11 = *(const uint4*)(r1 + 16);
            acc16_fp8(a, v00); acc16_fp8(a + 16, v01);
            acc16_fp8(a, v10); acc16_fp8(a + 16, v11);
        }
        if (e < end) {
            const u8* r = tp + (long)col[e] * 128;
            acc16_fp8(a, *(const uint4*)r);
            acc16_fp8(a + 16, *(const uint4*)(r + 16));
        }
        const float dn = dis[node];
        uint pk[16];
#pragma unroll
        for (int j = 0; j < 16; ++j) {
            float lo = fmaxf(a[2 * j] * dn + bvec[ch + 2 * j], 0.0f);
            float hi = fmaxf(a[2 * j + 1] * dn + bvec[ch + 2 * j + 1], 0.0f);
            pk[j] = (unsigned)f2b(lo) | ((unsigned)f2b(hi) << 16);
        }
        bfu* hrow = &Hs[nrow * 136 + ch];
#pragma unroll
        for (int q = 0; q < 4; ++q)
            *(uint4*)(hrow + q * 8) = make_uint4(pk[4 * q], pk[4 * q + 1], pk[4 * q + 2], pk[4 * q + 3]);
    }
    __syncthreads();
    // ---- MFMA from LDS: 4 waves x 16 rows, K=128 ----
    const int w = t >> 6, l = t & 63, l15 = l & 15, lhi = l >> 4;
    f32x4 acc[8];
#pragma unroll
    for (int nf = 0; nf < 8; ++nf) acc[nf] = (f32x4)0.0f;
#pragma unroll
    for (int ks = 0; ks < 4; ++ks) {
        short8 af = *(const short8*)&Hs[(w * 16 + l15) * 136 + ks * 32 + lhi * 8];
        const bfu* wp = Wp + ((long)(ks * 8) * 64 + l) * 8;
#pragma unroll
        for (int nf = 0; nf < 8; ++nf) {
            short8 wf = *(const short8*)(wp + (long)nf * 64 * 8);
            acc[nf] = __builtin_amdgcn_mfma_f32_16x16x32_bf16(wf, af, acc[nf], 0, 0, 0);
        }
    }
    int row = blockIdx.x * 64 + w * 16 + l15;
    if (row < M) {
        float sc = dis[row];
        int nb0 = lhi * 4;
#pragma unroll
        for (int nf = 0; nf < 8; ++nf) {
            if (OUT_BF16) {
                uint2 pko;
                pko.x = (unsigned)f2b(acc[nf][0] * sc) | ((unsigned)f2b(acc[nf][1] * sc) << 16);
                pko.y = (unsigned)f2b(acc[nf][2] * sc) | ((unsigned)f2b(acc[nf][3] * sc) << 16);
                *(uint2*)&tnext16[(long)row * 128 + nf * 16 + nb0] = pko;
            } else {
                unsigned pko = pk4_fp8(acc[nf][0] * sc, acc[nf][1] * sc,
                                       acc[nf][2] * sc, acc[nf][3] * sc);
                *(unsigned*)&tnext8[(long)row * 128 + nf * 16 + nb0] = pko;
            }
        }
    }
}

// ---------------- standalone CSR gather agg (layer 3; bf16 t3 -> bf16 h3) ----------------
__global__ __launch_bounds__(256) void k_agg(const int* __restrict__ row_ptr,
                                             const int* __restrict__ col,
                                             const float* __restrict__ dis,
                                             const bfu* __restrict__ tbuf,
                                             const float* __restrict__ b,
                                             bfu* __restrict__ h) {
    const int t = threadIdx.x;
    const int node = blockIdx.x * 8 + (t >> 5);
    const int lane = t & 31;
    if (node >= N_NODES) return;
    const int q = lane << 2;

    uint2 sv = *(const uint2*)&tbuf[(long)node * 128 + q];
    float a0 = b2f(sv.x & 0xffff);
    float a1 = b2f(sv.x >> 16);
    float a2 = b2f(sv.y & 0xffff);
    float a3 = b2f(sv.y >> 16);

    int e = row_ptr[node];
    const int end = row_ptr[node + 1];
    for (; e + 3 < end; e += 4) {
        int s0 = col[e], s1 = col[e + 1], s2 = col[e + 2], s3 = col[e + 3];
        uint2 v0 = *(const uint2*)&tbuf[(long)s0 * 128 + q];
        uint2 v1 = *(const uint2*)&tbuf[(long)s1 * 128 + q];
        uint2 v2 = *(const uint2*)&tbuf[(long)s2 * 128 + q];
        uint2 v3 = *(const uint2*)&tbuf[(long)s3 * 128 + q];
        a0 += (b2f(v0.x & 0xffff) + b2f(v1.x & 0xffff)) +
              (b2f(v2.x & 0xffff) + b2f(v3.x & 0xffff));
        a1 += (b2f(v0.x >> 16) + b2f(v1.x >> 16)) +
              (b2f(v2.x >> 16) + b2f(v3.x >> 16));
        a2 += (b2f(v0.y & 0xffff) + b2f(v1.y & 0xffff)) +
              (b2f(v2.y & 0xffff) + b2f(v3.y & 0xffff));
        a3 += (b2f(v0.y >> 16) + b2f(v1.y >> 16)) +
              (b2f(v2.y >> 16) + b2f(v3.y >> 16));
    }
    for (; e < end; ++e) {
        int s0 = col[e];
        uint2 v0 = *(const uint2*)&tbuf[(long)s0 * 128 + q];
        a0 += b2f(v0.x & 0xffff);
        a1 += b2f(v0.x >> 16);
        a2 += b2f(v0.y & 0xffff);
        a3 += b2f(v0.y >> 16);
    }
    const float dn = dis[node];
    float4 bb = *(const float4*)&b[q];
    float o0 = fmaxf(a0 * dn + bb.x, 0.0f);
    float o1 = fmaxf(a1 * dn + bb.y, 0.0f);
    float o2 = fmaxf(a2 * dn + bb.z, 0.0f);
    float o3 = fmaxf(a3 * dn + bb.w, 0.0f);
    uint2 pk;
    pk.x = (unsigned)f2b(o0) | ((unsigned)f2b(o1) << 16);
    pk.y = (unsigned)f2b(o2) | ((unsigned)f2b(o3) << 16);
    *(uint2*)&h[(long)node * 128 + q] = pk;
}

// ---------------- fused pool (mean over segment; h already relu'd) + MLP head ----------------
__global__ __launch_bounds__(128) void k_pool_head(const int* __restrict__ bounds,
                                                   const bfu* __restrict__ h,
                                                   const float* __restrict__ fw1, const float* __restrict__ fb1,
                                                   const float* __restrict__ fw2, const float* __restrict__ fb2,
                                                   float* __restrict__ out) {
    const int g = blockIdx.x;
    const int t = threadIdx.x;
    const int s = bounds[g], e = bounds[g + 1];
    float sum = 0.0f;
    int n = s;
    for (; n + 1 < e; n += 2) {
        sum += b2f(h[(long)n * 128 + t]);
        sum += b2f(h[(long)(n + 1) * 128 + t]);
    }
    if (n < e) sum += b2f(h[(long)n * 128 + t]);

    __shared__ float sg[128];
    __shared__ float sh[32];
    float inv = 1.0f / fmaxf((float)(e - s), 1.0f);
    sg[t] = sum * inv;
    __syncthreads();
    if (t < 32) {
        float a = fb1[t];
#pragma unroll 8
        for (int k = 0; k < 128; ++k) a += sg[k] * fw1[k * 32 + t];
        sh[t] = fmaxf(a, 0.0f);
    }
    __syncthreads();
    if (t == 0) {
        float l0 = fb2[0], l1 = fb2[1];
        for (int k = 0; k < 32; ++k) {
            l0 += sh[k] * fw2[k * 2];
            l1 += sh[k] * fw2[k * 2 + 1];
        }
        float m = fmaxf(l0, l1);
        float lse = m + logf(expf(l0 - m) + expf(l1 - m));
        out[g * 2 + 0] = l0 - lse;
        out[g * 2 + 1] = l1 - lse;
    }
}

extern "C" void kernel_launch(void* const* d_in, const int* in_sizes, int n_in,
                              void* d_out, int out_size, void* d_ws, size_t ws_size,
                              hipStream_t stream) {
    const float* x  = (const float*)d_in[0];
    const int* ei   = (const int*)d_in[1];
    const int* batch = (const int*)d_in[2];
    const float* W1 = (const float*)d_in[3];
    const float* b1 = (const float*)d_in[4];
    const float* W2 = (const float*)d_in[5];
    const float* b2 = (const float*)d_in[6];
    const float* W3 = (const float*)d_in[7];
    const float* b3 = (const float*)d_in[8];
    const float* fw1 = (const float*)d_in[9];
    const float* fb1 = (const float*)d_in[10];
    const float* fw2 = (const float*)d_in[11];
    const float* fb2 = (const float*)d_in[12];
    float* out = (float*)d_out;

    const int* src = ei;
    const int* dst = ei + N_EDGES;

    // workspace layout (all chunks multiple of 16 B)
    char* ws = (char*)d_ws;
    int*      cnt_bb      = (int*)ws;                            // 256*392
    int*      btot        = cnt_bb + A_BLOCKS * BSTRIDE;         // 392
    int*      bucket_base = btot + BSTRIDE;                      // 392+8
    unsigned* staging     = (unsigned*)(bucket_base + BSTRIDE + 8);  // E
    int*      row_ptr     = (int*)(staging + N_EDGES);           // N+4
    float*    dis         = (float*)(row_ptr + N_NODES + 4);     // N
    int*      col         = (int*)(dis + N_NODES);               // E
    int*      bounds      = col + N_EDGES;                       // G+1 (+pad)
    bfu*      wpack1      = (bfu*)(bounds + N_GRAPHS + 8);       // 32768 bfu (K=256)
    bfu*      wpack2      = wpack1 + 32768;                      // 16384 bfu (K=128)
    bfu*      wpack3      = wpack2 + 16384;                      // 16384 bfu
    u8*       bufA8       = (u8*)(wpack3 + 16384);               // N*128 fp8 (t1)
    u8*       bufB8       = bufA8 + (long)N_NODES * 128;         // N*128 fp8 (t2)
    bfu*      bufC        = (bfu*)(bufB8 + (long)N_NODES * 128); // N*128 bf16 (t3)
    bfu*      bufD        = bufC + (long)N_NODES * 128;          // N*128 bf16 (h3)

    // ---- CSR build (counting sort) + merged wpack/bounds ----
    k_hist<<<A_BLOCKS, 256, 0, stream>>>(dst, cnt_bb);
    k_scan_blocks<<<NB_BUCKETS, 256, 0, stream>>>(cnt_bb, btot);
    k_scan_buckets<<<1, 512, 0, stream>>>(btot, bucket_base);
    k_stage<<<A_BLOCKS, 256, 0, stream>>>(src, dst, cnt_bb, bucket_base, staging);
    k_bucket<<<NB_BUCKETS, 256, 0, stream>>>(staging, bucket_base, row_ptr, dis, col);
    k_misc<<<36, 256, 0, stream>>>(W1, W2, W3, wpack1, wpack2, wpack3, batch, bounds);

    const int mm1Grid = (N_NODES + 63) / 64;      // 1563
    const int fusedGrid = (N_NODES + 63) / 64;    // 1563
    const int aggGrid = (N_NODES + 7) / 8;        // 12500

    // layer 1: t1(fp8) = (x @ W1) * dis
    k_mm1<<<mm1Grid, 256, 0, stream>>>(x, wpack1, dis, bufA8, N_NODES);
    // fused: t2(fp8) = (relu(dis*gather(t1)+b1) @ W2) * dis
    k_agg_mm<false><<<fusedGrid, 256, 0, stream>>>(row_ptr, col, dis, bufA8, b1, wpack2,
                                                   nullptr, bufB8, N_NODES);
    // fused: t3(bf16) = (relu(dis*gather(t2)+b2) @ W3) * dis
    k_agg_mm<true><<<fusedGrid, 256, 0, stream>>>(row_ptr, col, dis, bufB8, b2, wpack3,
                                                  bufC, nullptr, N_NODES);
    // layer3 agg (bf16): h3 = relu(dis*gather(t3)+b3)
    k_agg<<<aggGrid, 256, 0, stream>>>(row_ptr, col, dis, bufC, b3, bufD);

    // fused pool + head
    k_pool_head<<<N_GRAPHS, 128, 0, stream>>>(bounds, bufD, fw1, fb1, fw2, fb2, out);
}

// Round 12
// 310.226 us; speedup vs baseline: 1.3061x; 1.0896x over previous
//
#include <hip/hip_runtime.h>
#include <hip/hip_bf16.h>
#include <math.h>

#define N_NODES 100000
#define N_EDGES 1600000
#define F_IN 256
#define H_DIM 128
#define N_GRAPHS 1000

#define NB_BUCKETS ((N_NODES + 255) >> 8)   // 391 buckets of 256 nodes
#define BSTRIDE 392
#define A_BLOCKS 256
#define EPB (N_EDGES / A_BLOCKS)            // 6250 edges per block (exact)

typedef unsigned short bfu;  // bf16 bit pattern
typedef unsigned char u8;
typedef short short8 __attribute__((ext_vector_type(8)));   // 8 bf16 = 4 VGPR
typedef float f32x4 __attribute__((ext_vector_type(4)));    // MFMA accum
typedef float f32x2 __attribute__((ext_vector_type(2)));

__device__ __forceinline__ float b2f(unsigned u) {
    union { unsigned int i; float f; } v;
    v.i = u << 16;
    return v.f;
}
__device__ __forceinline__ bfu f2b(float f) {
    __hip_bfloat16 h = __float2bfloat16(f);  // RNE
    return *reinterpret_cast<bfu*>(&h);
}
// 4 f32 -> 4 fp8(e4m3) bytes packed in a dword (HW cvt, RNE+sat)
__device__ __forceinline__ unsigned pk4_fp8(float v0, float v1, float v2, float v3) {
    int r = __builtin_amdgcn_cvt_pk_fp8_f32(v0, v1, 0, false);
    r = __builtin_amdgcn_cvt_pk_fp8_f32(v2, v3, r, true);
    return (unsigned)r;
}
// accumulate 4 fp8 (one dword) into a[0..3]
__device__ __forceinline__ void acc4_fp8(float* a, unsigned v) {
    f32x2 p;
    p = __builtin_amdgcn_cvt_pk_f32_fp8((int)v, false); a[0] += p.x; a[1] += p.y;
    p = __builtin_amdgcn_cvt_pk_f32_fp8((int)v, true);  a[2] += p.x; a[3] += p.y;
}
// accumulate 16 fp8 (one uint4) into a[0..15]
__device__ __forceinline__ void acc16_fp8(float* a, uint4 v) {
    acc4_fp8(a, v.x); acc4_fp8(a + 4, v.y); acc4_fp8(a + 8, v.z); acc4_fp8(a + 12, v.w);
}

// ---------------- CSR build: bucketed counting sort ----------------
__global__ __launch_bounds__(256) void k_hist(const int* __restrict__ dst,
                                              int* __restrict__ cnt_bb) {
    __shared__ int h[BSTRIDE];
    const int t = threadIdx.x;
    for (int i = t; i < BSTRIDE; i += 256) h[i] = 0;
    __syncthreads();
    const int base = blockIdx.x * EPB;
    for (int i = t; i < EPB; i += 256) atomicAdd(&h[dst[base + i] >> 8], 1);
    __syncthreads();
    for (int i = t; i < NB_BUCKETS; i += 256) cnt_bb[blockIdx.x * BSTRIDE + i] = h[i];
}

__global__ __launch_bounds__(256) void k_scan_blocks(int* __restrict__ cnt_bb,
                                                     int* __restrict__ btot) {
    __shared__ int s[256];
    const int t = threadIdx.x;
    const int b = blockIdx.x;
    int v = cnt_bb[t * BSTRIDE + b];
    s[t] = v;
    __syncthreads();
    for (int off = 1; off < 256; off <<= 1) {
        int u = (t >= off) ? s[t - off] : 0;
        __syncthreads();
        s[t] += u;
        __syncthreads();
    }
    cnt_bb[t * BSTRIDE + b] = s[t] - v;
    if (t == 255) btot[b] = s[255];
}

__global__ __launch_bounds__(512) void k_scan_buckets(const int* __restrict__ btot,
                                                      int* __restrict__ bucket_base) {
    __shared__ int s[512];
    const int t = threadIdx.x;
    int v = (t < NB_BUCKETS) ? btot[t] : 0;
    s[t] = v;
    __syncthreads();
    for (int off = 1; off < 512; off <<= 1) {
        int u = (t >= off) ? s[t - off] : 0;
        __syncthreads();
        s[t] += u;
        __syncthreads();
    }
    if (t < NB_BUCKETS) bucket_base[t] = s[t] - v;
    if (t == 0) bucket_base[NB_BUCKETS] = N_EDGES;
}

__global__ __launch_bounds__(256) void k_stage(const int* __restrict__ src,
                                               const int* __restrict__ dst,
                                               const int* __restrict__ cnt_bb,
                                               const int* __restrict__ bucket_base,
                                               unsigned* __restrict__ staging) {
    __shared__ int cur[BSTRIDE];
    const int t = threadIdx.x;
    const int blk = blockIdx.x;
    for (int i = t; i < NB_BUCKETS; i += 256)
        cur[i] = bucket_base[i] + cnt_bb[blk * BSTRIDE + i];
    __syncthreads();
    const int base = blk * EPB;
    for (int i = t; i < EPB; i += 256) {
        int d = dst[base + i];
        int s = src[base + i];
        int b = d >> 8;
        int pos = atomicAdd(&cur[b], 1);
        staging[pos] = (unsigned)s | ((unsigned)(d & 255) << 24);
    }
}

__global__ __launch_bounds__(256) void k_bucket(const unsigned* __restrict__ staging,
                                                const int* __restrict__ bucket_base,
                                                int* __restrict__ row_ptr,
                                                float* __restrict__ dis,
                                                int* __restrict__ col) {
    __shared__ int h[256];
    __shared__ int sc[256];
    __shared__ int cur[256];
    const int t = threadIdx.x;
    const int b = blockIdx.x;
    const int s0 = bucket_base[b];
    const int ne = bucket_base[b + 1] - s0;
    h[t] = 0;
    __syncthreads();
    for (int i = t; i < ne; i += 256) atomicAdd(&h[staging[s0 + i] >> 24], 1);
    __syncthreads();
    int myc = h[t];
    sc[t] = myc;
    __syncthreads();
    for (int off = 1; off < 256; off <<= 1) {
        int u = (t >= off) ? sc[t - off] : 0;
        __syncthreads();
        sc[t] += u;
        __syncthreads();
    }
    int excl = sc[t] - myc;
    int node = b * 256 + t;
    if (node <= N_NODES) row_ptr[node] = s0 + excl;
    if (node < N_NODES) dis[node] = rsqrtf((float)(myc + 1));
    cur[t] = s0 + excl;
    __syncthreads();
    for (int i = t; i < ne; i += 256) {
        unsigned u = staging[s0 + i];
        int pos = atomicAdd(&cur[u >> 24], 1);
        col[pos] = (int)(u & 0xFFFFFFu);
    }
}

// ---------------- merged: W pre-packs + graph bounds (one launch) ----------------
__device__ __forceinline__ void wpack_one(const float* __restrict__ W,
                                          bfu* __restrict__ Wp, int u) {
    int lane = u & 63;
    int nf = (u >> 6) & 7;
    int ks = u >> 9;
    int k = ks * 32 + (lane >> 4) * 8;
    int n = nf * 16 + (lane & 15);
    bfu o[8];
#pragma unroll
    for (int j = 0; j < 8; ++j) o[j] = f2b(W[(k + j) * 128 + n]);
    uint4 pk;
    pk.x = (unsigned)o[0] | ((unsigned)o[1] << 16);
    pk.y = (unsigned)o[2] | ((unsigned)o[3] << 16);
    pk.z = (unsigned)o[4] | ((unsigned)o[5] << 16);
    pk.w = (unsigned)o[6] | ((unsigned)o[7] << 16);
    *(uint4*)&Wp[u * 8] = pk;
}

__global__ __launch_bounds__(256) void k_misc(const float* __restrict__ W1,
                                              const float* __restrict__ W2,
                                              const float* __restrict__ W3,
                                              bfu* __restrict__ wp1, bfu* __restrict__ wp2,
                                              bfu* __restrict__ wp3,
                                              const int* __restrict__ batch,
                                              int* __restrict__ bounds) {
    const int b = blockIdx.x, t = threadIdx.x;
    if (b < 16) {
        wpack_one(W1, wp1, b * 256 + t);
    } else if (b < 24) {
        wpack_one(W2, wp2, (b - 16) * 256 + t);
    } else if (b < 32) {
        wpack_one(W3, wp3, (b - 24) * 256 + t);
    } else {
        int g = (b - 32) * 256 + t;
        if (g <= N_GRAPHS) {
            int lo = 0, hi = N_NODES;
            while (lo < hi) {
                int mid = (lo + hi) >> 1;
                if (batch[mid] < g) lo = mid + 1; else hi = mid;
            }
            bounds[g] = lo;
        }
    }
}

// ---------------- mm1: direct-to-register fragments; OUT = fp8 t1 ----------------
__global__ __launch_bounds__(256, 4) void k_mm1(const float* __restrict__ A,
                                                const bfu* __restrict__ Wp,
                                                const float* __restrict__ dis,
                                                u8* __restrict__ C8, int M) {
    const int t = threadIdx.x;
    const int w = t >> 6, l = t & 63, l15 = l & 15, lhi = l >> 4;
    const int row = blockIdx.x * 64 + w * 16 + l15;
    const int rowc = row < M ? row : M - 1;
    const float* ap = A + (long)rowc * 256 + lhi * 8;

    float4 va[8][2];
#pragma unroll
    for (int ks = 0; ks < 8; ++ks) {
        va[ks][0] = *(const float4*)(ap + ks * 32);
        va[ks][1] = *(const float4*)(ap + ks * 32 + 4);
    }

    f32x4 acc[8];
#pragma unroll
    for (int nf = 0; nf < 8; ++nf) acc[nf] = (f32x4)0.0f;

#pragma unroll
    for (int ks = 0; ks < 8; ++ks) {
        unsigned p0 = (unsigned)f2b(va[ks][0].x) | ((unsigned)f2b(va[ks][0].y) << 16);
        unsigned p1 = (unsigned)f2b(va[ks][0].z) | ((unsigned)f2b(va[ks][0].w) << 16);
        unsigned p2 = (unsigned)f2b(va[ks][1].x) | ((unsigned)f2b(va[ks][1].y) << 16);
        unsigned p3 = (unsigned)f2b(va[ks][1].z) | ((unsigned)f2b(va[ks][1].w) << 16);
        uint4 afu = make_uint4(p0, p1, p2, p3);
        short8 af = *(short8*)&afu;
        const bfu* wp = Wp + ((long)(ks * 8) * 64 + l) * 8;
#pragma unroll
        for (int nf = 0; nf < 8; ++nf) {
            short8 wf = *(const short8*)(wp + (long)nf * 64 * 8);
            acc[nf] = __builtin_amdgcn_mfma_f32_16x16x32_bf16(wf, af, acc[nf], 0, 0, 0);
        }
    }
    if (row < M) {
        float sc = dis[row];
        int nb0 = lhi * 4;
#pragma unroll
        for (int nf = 0; nf < 8; ++nf) {
            unsigned pk = pk4_fp8(acc[nf][0] * sc, acc[nf][1] * sc,
                                  acc[nf][2] * sc, acc[nf][3] * sc);
            *(unsigned*)&C8[(long)row * 128 + nf * 16 + nb0] = pk;
        }
    }
}

// ---------------- FUSED agg+mm: fp8 gather -> bf16 LDS -> MFMA -> fp8 out ----------------
// 256 thr; 64 dst nodes/block; 4 lanes/node x 32ch.
__global__ __launch_bounds__(256) void k_agg_mm(const int* __restrict__ row_ptr,
                                                const int* __restrict__ col,
                                                const float* __restrict__ dis,
                                                const u8* __restrict__ tprev8,
                                                const float* __restrict__ bvec,
                                                const bfu* __restrict__ Wp,
                                                u8* __restrict__ tnext8, int M) {
    __shared__ bfu Hs[64 * 136];  // 64 rows x 128 bf16, pitch 272 B
    const int t = threadIdx.x;
    const int nrow = t >> 2;                 // 0..63
    const int node = blockIdx.x * 64 + nrow;
    const int lz = t & 3;
    const int ch = lz * 32;                  // this lane's 32 channels (32 fp8 bytes)

    if (node < M) {
        float a[32];
#pragma unroll
        for (int j = 0; j < 32; ++j) a[j] = 0.0f;
        const u8* tp = tprev8 + ch;
        {
            const u8* r = tp + (long)node * 128;
            acc16_fp8(a, *(const uint4*)r);
            acc16_fp8(a + 16, *(const uint4*)(r + 16));
        }
        int e = row_ptr[node];
        const int end = row_ptr[node + 1];
        for (; e + 1 < end; e += 2) {
            int s0 = col[e], s1 = col[e + 1];
            const u8* r0 = tp + (long)s0 * 128;
            const u8* r1 = tp + (long)s1 * 128;
            uint4 v00 = *(const uint4*)r0;
            uint4 v01 = *(const uint4*)(r0 + 16);
            uint4 v10 = *(const uint4*)r1;
            uint4 v11 = *(const uint4*)(r1 + 16);
            acc16_fp8(a, v00); acc16_fp8(a + 16, v01);
            acc16_fp8(a, v10); acc16_fp8(a + 16, v11);
        }
        if (e < end) {
            const u8* r = tp + (long)col[e] * 128;
            acc16_fp8(a, *(const uint4*)r);
            acc16_fp8(a + 16, *(const uint4*)(r + 16));
        }
        const float dn = dis[node];
        uint pk[16];
#pragma unroll
        for (int j = 0; j < 16; ++j) {
            float lo = fmaxf(a[2 * j] * dn + bvec[ch + 2 * j], 0.0f);
            float hi = fmaxf(a[2 * j + 1] * dn + bvec[ch + 2 * j + 1], 0.0f);
            pk[j] = (unsigned)f2b(lo) | ((unsigned)f2b(hi) << 16);
        }
        bfu* hrow = &Hs[nrow * 136 + ch];
#pragma unroll
        for (int q = 0; q < 4; ++q)
            *(uint4*)(hrow + q * 8) = make_uint4(pk[4 * q], pk[4 * q + 1], pk[4 * q + 2], pk[4 * q + 3]);
    }
    __syncthreads();
    // ---- MFMA from LDS: 4 waves x 16 rows, K=128 ----
    const int w = t >> 6, l = t & 63, l15 = l & 15, lhi = l >> 4;
    f32x4 acc[8];
#pragma unroll
    for (int nf = 0; nf < 8; ++nf) acc[nf] = (f32x4)0.0f;
#pragma unroll
    for (int ks = 0; ks < 4; ++ks) {
        short8 af = *(const short8*)&Hs[(w * 16 + l15) * 136 + ks * 32 + lhi * 8];
        const bfu* wp = Wp + ((long)(ks * 8) * 64 + l) * 8;
#pragma unroll
        for (int nf = 0; nf < 8; ++nf) {
            short8 wf = *(const short8*)(wp + (long)nf * 64 * 8);
            acc[nf] = __builtin_amdgcn_mfma_f32_16x16x32_bf16(wf, af, acc[nf], 0, 0, 0);
        }
    }
    int row = blockIdx.x * 64 + w * 16 + l15;
    if (row < M) {
        float sc = dis[row];
        int nb0 = lhi * 4;
#pragma unroll
        for (int nf = 0; nf < 8; ++nf) {
            unsigned pko = pk4_fp8(acc[nf][0] * sc, acc[nf][1] * sc,
                                   acc[nf][2] * sc, acc[nf][3] * sc);
            *(unsigned*)&tnext8[(long)row * 128 + nf * 16 + nb0] = pko;
        }
    }
}

// ---------------- layer-3 agg: fp8 t3 gather -> bf16 h3 ----------------
__global__ __launch_bounds__(256) void k_agg8(const int* __restrict__ row_ptr,
                                              const int* __restrict__ col,
                                              const float* __restrict__ dis,
                                              const u8* __restrict__ t8,
                                              const float* __restrict__ b,
                                              bfu* __restrict__ h) {
    const int t = threadIdx.x;
    const int node = blockIdx.x * 8 + (t >> 5);
    const int lane = t & 31;
    if (node >= N_NODES) return;
    const int q = lane << 2;  // 4 channels per lane (4 fp8 bytes)

    const u8* tp = t8 + q;
    float a[4] = {0.f, 0.f, 0.f, 0.f};
    acc4_fp8(a, *(const unsigned*)&tp[(long)node * 128]);  // self term

    int e = row_ptr[node];
    const int end = row_ptr[node + 1];
    for (; e + 3 < end; e += 4) {
        int s0 = col[e], s1 = col[e + 1], s2 = col[e + 2], s3 = col[e + 3];
        unsigned v0 = *(const unsigned*)&tp[(long)s0 * 128];
        unsigned v1 = *(const unsigned*)&tp[(long)s1 * 128];
        unsigned v2 = *(const unsigned*)&tp[(long)s2 * 128];
        unsigned v3 = *(const unsigned*)&tp[(long)s3 * 128];
        acc4_fp8(a, v0); acc4_fp8(a, v1); acc4_fp8(a, v2); acc4_fp8(a, v3);
    }
    for (; e < end; ++e)
        acc4_fp8(a, *(const unsigned*)&tp[(long)col[e] * 128]);

    const float dn = dis[node];
    float4 bb = *(const float4*)&b[q];
    float o0 = fmaxf(a[0] * dn + bb.x, 0.0f);
    float o1 = fmaxf(a[1] * dn + bb.y, 0.0f);
    float o2 = fmaxf(a[2] * dn + bb.z, 0.0f);
    float o3 = fmaxf(a[3] * dn + bb.w, 0.0f);
    uint2 pk;
    pk.x = (unsigned)f2b(o0) | ((unsigned)f2b(o1) << 16);
    pk.y = (unsigned)f2b(o2) | ((unsigned)f2b(o3) << 16);
    *(uint2*)&h[(long)node * 128 + q] = pk;
}

// ---------------- fused pool (mean over segment; h already relu'd) + MLP head ----------------
__global__ __launch_bounds__(128) void k_pool_head(const int* __restrict__ bounds,
                                                   const bfu* __restrict__ h,
                                                   const float* __restrict__ fw1, const float* __restrict__ fb1,
                                                   const float* __restrict__ fw2, const float* __restrict__ fb2,
                                                   float* __restrict__ out) {
    const int g = blockIdx.x;
    const int t = threadIdx.x;
    const int s = bounds[g], e = bounds[g + 1];
    float sum = 0.0f;
    int n = s;
    for (; n + 1 < e; n += 2) {
        sum += b2f(h[(long)n * 128 + t]);
        sum += b2f(h[(long)(n + 1) * 128 + t]);
    }
    if (n < e) sum += b2f(h[(long)n * 128 + t]);

    __shared__ float sg[128];
    __shared__ float sh[32];
    float inv = 1.0f / fmaxf((float)(e - s), 1.0f);
    sg[t] = sum * inv;
    __syncthreads();
    if (t < 32) {
        float a = fb1[t];
#pragma unroll 8
        for (int k = 0; k < 128; ++k) a += sg[k] * fw1[k * 32 + t];
        sh[t] = fmaxf(a, 0.0f);
    }
    __syncthreads();
    if (t == 0) {
        float l0 = fb2[0], l1 = fb2[1];
        for (int k = 0; k < 32; ++k) {
            l0 += sh[k] * fw2[k * 2];
            l1 += sh[k] * fw2[k * 2 + 1];
        }
        float m = fmaxf(l0, l1);
        float lse = m + logf(expf(l0 - m) + expf(l1 - m));
        out[g * 2 + 0] = l0 - lse;
        out[g * 2 + 1] = l1 - lse;
    }
}

extern "C" void kernel_launch(void* const* d_in, const int* in_sizes, int n_in,
                              void* d_out, int out_size, void* d_ws, size_t ws_size,
                              hipStream_t stream) {
    const float* x  = (const float*)d_in[0];
    const int* ei   = (const int*)d_in[1];
    const int* batch = (const int*)d_in[2];
    const float* W1 = (const float*)d_in[3];
    const float* b1 = (const float*)d_in[4];
    const float* W2 = (const float*)d_in[5];
    const float* b2 = (const float*)d_in[6];
    const float* W3 = (const float*)d_in[7];
    const float* b3 = (const float*)d_in[8];
    const float* fw1 = (const float*)d_in[9];
    const float* fb1 = (const float*)d_in[10];
    const float* fw2 = (const float*)d_in[11];
    const float* fb2 = (const float*)d_in[12];
    float* out = (float*)d_out;

    const int* src = ei;
    const int* dst = ei + N_EDGES;

    // workspace layout (all chunks multiple of 16 B)
    char* ws = (char*)d_ws;
    int*      cnt_bb      = (int*)ws;                            // 256*392
    int*      btot        = cnt_bb + A_BLOCKS * BSTRIDE;         // 392
    int*      bucket_base = btot + BSTRIDE;                      // 392+8
    unsigned* staging     = (unsigned*)(bucket_base + BSTRIDE + 8);  // E
    int*      row_ptr     = (int*)(staging + N_EDGES);           // N+4
    float*    dis         = (float*)(row_ptr + N_NODES + 4);     // N
    int*      col         = (int*)(dis + N_NODES);               // E
    int*      bounds      = col + N_EDGES;                       // G+1 (+pad)
    bfu*      wpack1      = (bfu*)(bounds + N_GRAPHS + 8);       // 32768 bfu (K=256)
    bfu*      wpack2      = wpack1 + 32768;                      // 16384 bfu (K=128)
    bfu*      wpack3      = wpack2 + 16384;                      // 16384 bfu
    u8*       bufA8       = (u8*)(wpack3 + 16384);               // N*128 fp8 (t1)
    u8*       bufB8       = bufA8 + (long)N_NODES * 128;         // N*128 fp8 (t2)
    u8*       bufC8       = bufB8 + (long)N_NODES * 128;         // N*128 fp8 (t3)
    bfu*      bufD        = (bfu*)(bufC8 + (long)N_NODES * 128); // N*128 bf16 (h3)

    // ---- CSR build (counting sort) + merged wpack/bounds ----
    k_hist<<<A_BLOCKS, 256, 0, stream>>>(dst, cnt_bb);
    k_scan_blocks<<<NB_BUCKETS, 256, 0, stream>>>(cnt_bb, btot);
    k_scan_buckets<<<1, 512, 0, stream>>>(btot, bucket_base);
    k_stage<<<A_BLOCKS, 256, 0, stream>>>(src, dst, cnt_bb, bucket_base, staging);
    k_bucket<<<NB_BUCKETS, 256, 0, stream>>>(staging, bucket_base, row_ptr, dis, col);
    k_misc<<<36, 256, 0, stream>>>(W1, W2, W3, wpack1, wpack2, wpack3, batch, bounds);

    const int mm1Grid = (N_NODES + 63) / 64;      // 1563
    const int fusedGrid = (N_NODES + 63) / 64;    // 1563
    const int aggGrid = (N_NODES + 7) / 8;        // 12500

    // layer 1: t1(fp8) = (x @ W1) * dis
    k_mm1<<<mm1Grid, 256, 0, stream>>>(x, wpack1, dis, bufA8, N_NODES);
    // fused: t2(fp8) = (relu(dis*gather(t1)+b1) @ W2) * dis
    k_agg_mm<<<fusedGrid, 256, 0, stream>>>(row_ptr, col, dis, bufA8, b1, wpack2, bufB8, N_NODES);
    // fused: t3(fp8) = (relu(dis*gather(t2)+b2) @ W3) * dis
    k_agg_mm<<<fusedGrid, 256, 0, stream>>>(row_ptr, col, dis, bufB8, b2, wpack3, bufC8, N_NODES);
    // layer3 agg: h3(bf16) = relu(dis*gather(t3)+b3)
    k_agg8<<<aggGrid, 256, 0, stream>>>(row_ptr, col, dis, bufC8, b3, bufD);

    // fused pool + head
    k_pool_head<<<N_GRAPHS, 128, 0, stream>>>(bounds, bufD, fw1, fb1, fw2, fb2, out);
}

// Round 13
// 305.270 us; speedup vs baseline: 1.3273x; 1.0162x over previous
//
#include <hip/hip_runtime.h>
#include <hip/hip_bf16.h>
#include <math.h>

#define N_NODES 100000
#define N_EDGES 1600000
#define F_IN 256
#define H_DIM 128
#define N_GRAPHS 1000

#define NB_BUCKETS ((N_NODES + 255) >> 8)   // 391 buckets of 256 nodes
#define BSTRIDE 392
#define A_BLOCKS 256
#define EPB (N_EDGES / A_BLOCKS)            // 6250 edges per block (exact)

typedef unsigned short bfu;  // bf16 bit pattern
typedef unsigned char u8;
typedef short short8 __attribute__((ext_vector_type(8)));   // 8 bf16 = 4 VGPR
typedef float f32x4 __attribute__((ext_vector_type(4)));    // MFMA accum
typedef float f32x2 __attribute__((ext_vector_type(2)));

__device__ __forceinline__ float b2f(unsigned u) {
    union { unsigned int i; float f; } v;
    v.i = u << 16;
    return v.f;
}
__device__ __forceinline__ bfu f2b(float f) {
    __hip_bfloat16 h = __float2bfloat16(f);  // RNE
    return *reinterpret_cast<bfu*>(&h);
}
// 4 f32 -> 4 fp8(e4m3) bytes packed in a dword (HW cvt, RNE+sat)
__device__ __forceinline__ unsigned pk4_fp8(float v0, float v1, float v2, float v3) {
    int r = __builtin_amdgcn_cvt_pk_fp8_f32(v0, v1, 0, false);
    r = __builtin_amdgcn_cvt_pk_fp8_f32(v2, v3, r, true);
    return (unsigned)r;
}
// accumulate 4 fp8 (one dword) into a[0..3]
__device__ __forceinline__ void acc4_fp8(float* a, unsigned v) {
    f32x2 p;
    p = __builtin_amdgcn_cvt_pk_f32_fp8((int)v, false); a[0] += p.x; a[1] += p.y;
    p = __builtin_amdgcn_cvt_pk_f32_fp8((int)v, true);  a[2] += p.x; a[3] += p.y;
}

// ---------------- CSR build: bucketed counting sort ----------------
__global__ __launch_bounds__(256) void k_hist(const int* __restrict__ dst,
                                              int* __restrict__ cnt_bb) {
    __shared__ int h[BSTRIDE];
    const int t = threadIdx.x;
    for (int i = t; i < BSTRIDE; i += 256) h[i] = 0;
    __syncthreads();
    const int base = blockIdx.x * EPB;
    for (int i = t; i < EPB; i += 256) atomicAdd(&h[dst[base + i] >> 8], 1);
    __syncthreads();
    for (int i = t; i < NB_BUCKETS; i += 256) cnt_bb[blockIdx.x * BSTRIDE + i] = h[i];
}

__global__ __launch_bounds__(256) void k_scan_blocks(int* __restrict__ cnt_bb,
                                                     int* __restrict__ btot) {
    __shared__ int s[256];
    const int t = threadIdx.x;
    const int b = blockIdx.x;
    int v = cnt_bb[t * BSTRIDE + b];
    s[t] = v;
    __syncthreads();
    for (int off = 1; off < 256; off <<= 1) {
        int u = (t >= off) ? s[t - off] : 0;
        __syncthreads();
        s[t] += u;
        __syncthreads();
    }
    cnt_bb[t * BSTRIDE + b] = s[t] - v;
    if (t == 255) btot[b] = s[255];
}

__global__ __launch_bounds__(512) void k_scan_buckets(const int* __restrict__ btot,
                                                      int* __restrict__ bucket_base) {
    __shared__ int s[512];
    const int t = threadIdx.x;
    int v = (t < NB_BUCKETS) ? btot[t] : 0;
    s[t] = v;
    __syncthreads();
    for (int off = 1; off < 512; off <<= 1) {
        int u = (t >= off) ? s[t - off] : 0;
        __syncthreads();
        s[t] += u;
        __syncthreads();
    }
    if (t < NB_BUCKETS) bucket_base[t] = s[t] - v;
    if (t == 0) bucket_base[NB_BUCKETS] = N_EDGES;
}

__global__ __launch_bounds__(256) void k_stage(const int* __restrict__ src,
                                               const int* __restrict__ dst,
                                               const int* __restrict__ cnt_bb,
                                               const int* __restrict__ bucket_base,
                                               unsigned* __restrict__ staging) {
    __shared__ int cur[BSTRIDE];
    const int t = threadIdx.x;
    const int blk = blockIdx.x;
    for (int i = t; i < NB_BUCKETS; i += 256)
        cur[i] = bucket_base[i] + cnt_bb[blk * BSTRIDE + i];
    __syncthreads();
    const int base = blk * EPB;
    for (int i = t; i < EPB; i += 256) {
        int d = dst[base + i];
        int s = src[base + i];
        int b = d >> 8;
        int pos = atomicAdd(&cur[b], 1);
        staging[pos] = (unsigned)s | ((unsigned)(d & 255) << 24);
    }
}

__global__ __launch_bounds__(256) void k_bucket(const unsigned* __restrict__ staging,
                                                const int* __restrict__ bucket_base,
                                                int* __restrict__ row_ptr,
                                                float* __restrict__ dis,
                                                int* __restrict__ col) {
    __shared__ int h[256];
    __shared__ int sc[256];
    __shared__ int cur[256];
    const int t = threadIdx.x;
    const int b = blockIdx.x;
    const int s0 = bucket_base[b];
    const int ne = bucket_base[b + 1] - s0;
    h[t] = 0;
    __syncthreads();
    for (int i = t; i < ne; i += 256) atomicAdd(&h[staging[s0 + i] >> 24], 1);
    __syncthreads();
    int myc = h[t];
    sc[t] = myc;
    __syncthreads();
    for (int off = 1; off < 256; off <<= 1) {
        int u = (t >= off) ? sc[t - off] : 0;
        __syncthreads();
        sc[t] += u;
        __syncthreads();
    }
    int excl = sc[t] - myc;
    int node = b * 256 + t;
    if (node <= N_NODES) row_ptr[node] = s0 + excl;
    if (node < N_NODES) dis[node] = rsqrtf((float)(myc + 1));
    cur[t] = s0 + excl;
    __syncthreads();
    for (int i = t; i < ne; i += 256) {
        unsigned u = staging[s0 + i];
        int pos = atomicAdd(&cur[u >> 24], 1);
        col[pos] = (int)(u & 0xFFFFFFu);
    }
}

// ---------------- merged: W pre-packs + graph bounds (one launch) ----------------
__device__ __forceinline__ void wpack_one(const float* __restrict__ W,
                                          bfu* __restrict__ Wp, int u) {
    int lane = u & 63;
    int nf = (u >> 6) & 7;
    int ks = u >> 9;
    int k = ks * 32 + (lane >> 4) * 8;
    int n = nf * 16 + (lane & 15);
    bfu o[8];
#pragma unroll
    for (int j = 0; j < 8; ++j) o[j] = f2b(W[(k + j) * 128 + n]);
    uint4 pk;
    pk.x = (unsigned)o[0] | ((unsigned)o[1] << 16);
    pk.y = (unsigned)o[2] | ((unsigned)o[3] << 16);
    pk.z = (unsigned)o[4] | ((unsigned)o[5] << 16);
    pk.w = (unsigned)o[6] | ((unsigned)o[7] << 16);
    *(uint4*)&Wp[u * 8] = pk;
}

__global__ __launch_bounds__(256) void k_misc(const float* __restrict__ W1,
                                              const float* __restrict__ W2,
                                              const float* __restrict__ W3,
                                              bfu* __restrict__ wp1, bfu* __restrict__ wp2,
                                              bfu* __restrict__ wp3,
                                              const int* __restrict__ batch,
                                              int* __restrict__ bounds) {
    const int b = blockIdx.x, t = threadIdx.x;
    if (b < 16) {
        wpack_one(W1, wp1, b * 256 + t);
    } else if (b < 24) {
        wpack_one(W2, wp2, (b - 16) * 256 + t);
    } else if (b < 32) {
        wpack_one(W3, wp3, (b - 24) * 256 + t);
    } else {
        int g = (b - 32) * 256 + t;
        if (g <= N_GRAPHS) {
            int lo = 0, hi = N_NODES;
            while (lo < hi) {
                int mid = (lo + hi) >> 1;
                if (batch[mid] < g) lo = mid + 1; else hi = mid;
            }
            bounds[g] = lo;
        }
    }
}

// ---------------- mm1: direct-to-register fragments; OUT = fp8 t1 ----------------
__global__ __launch_bounds__(256, 4) void k_mm1(const float* __restrict__ A,
                                                const bfu* __restrict__ Wp,
                                                const float* __restrict__ dis,
                                                u8* __restrict__ C8, int M) {
    const int t = threadIdx.x;
    const int w = t >> 6, l = t & 63, l15 = l & 15, lhi = l >> 4;
    const int row = blockIdx.x * 64 + w * 16 + l15;
    const int rowc = row < M ? row : M - 1;
    const float* ap = A + (long)rowc * 256 + lhi * 8;

    float4 va[8][2];
#pragma unroll
    for (int ks = 0; ks < 8; ++ks) {
        va[ks][0] = *(const float4*)(ap + ks * 32);
        va[ks][1] = *(const float4*)(ap + ks * 32 + 4);
    }

    f32x4 acc[8];
#pragma unroll
    for (int nf = 0; nf < 8; ++nf) acc[nf] = (f32x4)0.0f;

#pragma unroll
    for (int ks = 0; ks < 8; ++ks) {
        unsigned p0 = (unsigned)f2b(va[ks][0].x) | ((unsigned)f2b(va[ks][0].y) << 16);
        unsigned p1 = (unsigned)f2b(va[ks][0].z) | ((unsigned)f2b(va[ks][0].w) << 16);
        unsigned p2 = (unsigned)f2b(va[ks][1].x) | ((unsigned)f2b(va[ks][1].y) << 16);
        unsigned p3 = (unsigned)f2b(va[ks][1].z) | ((unsigned)f2b(va[ks][1].w) << 16);
        uint4 afu = make_uint4(p0, p1, p2, p3);
        short8 af = *(short8*)&afu;
        const bfu* wp = Wp + ((long)(ks * 8) * 64 + l) * 8;
#pragma unroll
        for (int nf = 0; nf < 8; ++nf) {
            short8 wf = *(const short8*)(wp + (long)nf * 64 * 8);
            acc[nf] = __builtin_amdgcn_mfma_f32_16x16x32_bf16(wf, af, acc[nf], 0, 0, 0);
        }
    }
    if (row < M) {
        float sc = dis[row];
        int nb0 = lhi * 4;
#pragma unroll
        for (int nf = 0; nf < 8; ++nf) {
            unsigned pk = pk4_fp8(acc[nf][0] * sc, acc[nf][1] * sc,
                                  acc[nf][2] * sc, acc[nf][3] * sc);
            *(unsigned*)&C8[(long)row * 128 + nf * 16 + nb0] = pk;
        }
    }
}

// ---------------- agg8: fp8 t' gather -> bf16 h (8 nodes/block, 32 lanes/node, 8-edge unroll) ----------------
__global__ __launch_bounds__(256) void k_agg8(const int* __restrict__ row_ptr,
                                              const int* __restrict__ col,
                                              const float* __restrict__ dis,
                                              const u8* __restrict__ t8,
                                              const float* __restrict__ b,
                                              bfu* __restrict__ h) {
    const int t = threadIdx.x;
    const int node = blockIdx.x * 8 + (t >> 5);
    const int lane = t & 31;
    if (node >= N_NODES) return;
    const int q = lane << 2;  // 4 channels per lane (4 fp8 bytes)

    const u8* tp = t8 + q;
    float a[4] = {0.f, 0.f, 0.f, 0.f};
    acc4_fp8(a, *(const unsigned*)&tp[(long)node * 128]);  // self term

    int e = row_ptr[node];
    const int end = row_ptr[node + 1];
    for (; e + 7 < end; e += 8) {
        unsigned v[8];
#pragma unroll
        for (int j = 0; j < 8; ++j) v[j] = *(const unsigned*)&tp[(long)col[e + j] * 128];
#pragma unroll
        for (int j = 0; j < 8; ++j) acc4_fp8(a, v[j]);
    }
    for (; e + 3 < end; e += 4) {
        unsigned v0 = *(const unsigned*)&tp[(long)col[e] * 128];
        unsigned v1 = *(const unsigned*)&tp[(long)col[e + 1] * 128];
        unsigned v2 = *(const unsigned*)&tp[(long)col[e + 2] * 128];
        unsigned v3 = *(const unsigned*)&tp[(long)col[e + 3] * 128];
        acc4_fp8(a, v0); acc4_fp8(a, v1); acc4_fp8(a, v2); acc4_fp8(a, v3);
    }
    for (; e < end; ++e)
        acc4_fp8(a, *(const unsigned*)&tp[(long)col[e] * 128]);

    const float dn = dis[node];
    float4 bb = *(const float4*)&b[q];
    float o0 = fmaxf(a[0] * dn + bb.x, 0.0f);
    float o1 = fmaxf(a[1] * dn + bb.y, 0.0f);
    float o2 = fmaxf(a[2] * dn + bb.z, 0.0f);
    float o3 = fmaxf(a[3] * dn + bb.w, 0.0f);
    uint2 pk;
    pk.x = (unsigned)f2b(o0) | ((unsigned)f2b(o1) << 16);
    pk.y = (unsigned)f2b(o2) | ((unsigned)f2b(o3) << 16);
    *(uint2*)&h[(long)node * 128 + q] = pk;
}

// ---------------- mm2: bf16 h (streaming) @ W -> fp8 t' (dbuf LDS + reg prefetch) ----------------
__global__ __launch_bounds__(256) void k_mm2(const bfu* __restrict__ A,
                                             const bfu* __restrict__ Wp,
                                             const float* __restrict__ dis,
                                             u8* __restrict__ C8, int M) {
    __shared__ bfu As[2][64 * 40];
    const int t = threadIdx.x;
    const int w = t >> 6;
    const int l = t & 63;
    const int l15 = l & 15;
    const int lhi = l >> 4;
    const int row0 = blockIdx.x * 64;

    f32x4 acc[8];
#pragma unroll
    for (int nf = 0; nf < 8; ++nf) acc[nf] = (f32x4)0.0f;

    uint4 pb = make_uint4(0u, 0u, 0u, 0u);
    {
        int r = t >> 2, s = t & 3;
        if (row0 + r < M) pb = *(const uint4*)&A[(long)(row0 + r) * 128 + s * 8];
    }

    int buf = 0;
#pragma unroll
    for (int ks = 0; ks < 4; ++ks) {
        *(uint4*)&As[buf][(t >> 2) * 40 + (t & 3) * 8] = pb;
        if (ks + 1 < 4) {
            const int k0n = (ks + 1) * 32;
            int r = t >> 2, s = t & 3;
            pb = make_uint4(0u, 0u, 0u, 0u);
            if (row0 + r < M) pb = *(const uint4*)&A[(long)(row0 + r) * 128 + k0n + s * 8];
        }
        __syncthreads();
        short8 af = *(const short8*)&As[buf][(w * 16 + l15) * 40 + lhi * 8];
        const bfu* wp = Wp + ((long)(ks * 8) * 64 + l) * 8;
#pragma unroll
        for (int nf = 0; nf < 8; ++nf) {
            short8 wf = *(const short8*)(wp + (long)nf * 64 * 8);
            acc[nf] = __builtin_amdgcn_mfma_f32_16x16x32_bf16(wf, af, acc[nf], 0, 0, 0);
        }
        if (ks + 1 < 4) __syncthreads();
        buf ^= 1;
    }
    int row = row0 + w * 16 + l15;
    if (row < M) {
        float sc = dis[row];
        int nb0 = lhi * 4;
#pragma unroll
        for (int nf = 0; nf < 8; ++nf) {
            unsigned pko = pk4_fp8(acc[nf][0] * sc, acc[nf][1] * sc,
                                   acc[nf][2] * sc, acc[nf][3] * sc);
            *(unsigned*)&C8[(long)row * 128 + nf * 16 + nb0] = pko;
        }
    }
}

// ---------------- fused pool (mean over segment; h already relu'd) + MLP head ----------------
__global__ __launch_bounds__(128) void k_pool_head(const int* __restrict__ bounds,
                                                   const bfu* __restrict__ h,
                                                   const float* __restrict__ fw1, const float* __restrict__ fb1,
                                                   const float* __restrict__ fw2, const float* __restrict__ fb2,
                                                   float* __restrict__ out) {
    const int g = blockIdx.x;
    const int t = threadIdx.x;
    const int s = bounds[g], e = bounds[g + 1];
    float sum = 0.0f;
    int n = s;
    for (; n + 1 < e; n += 2) {
        sum += b2f(h[(long)n * 128 + t]);
        sum += b2f(h[(long)(n + 1) * 128 + t]);
    }
    if (n < e) sum += b2f(h[(long)n * 128 + t]);

    __shared__ float sg[128];
    __shared__ float sh[32];
    float inv = 1.0f / fmaxf((float)(e - s), 1.0f);
    sg[t] = sum * inv;
    __syncthreads();
    if (t < 32) {
        float a = fb1[t];
#pragma unroll 8
        for (int k = 0; k < 128; ++k) a += sg[k] * fw1[k * 32 + t];
        sh[t] = fmaxf(a, 0.0f);
    }
    __syncthreads();
    if (t == 0) {
        float l0 = fb2[0], l1 = fb2[1];
        for (int k = 0; k < 32; ++k) {
            l0 += sh[k] * fw2[k * 2];
            l1 += sh[k] * fw2[k * 2 + 1];
        }
        float m = fmaxf(l0, l1);
        float lse = m + logf(expf(l0 - m) + expf(l1 - m));
        out[g * 2 + 0] = l0 - lse;
        out[g * 2 + 1] = l1 - lse;
    }
}

extern "C" void kernel_launch(void* const* d_in, const int* in_sizes, int n_in,
                              void* d_out, int out_size, void* d_ws, size_t ws_size,
                              hipStream_t stream) {
    const float* x  = (const float*)d_in[0];
    const int* ei   = (const int*)d_in[1];
    const int* batch = (const int*)d_in[2];
    const float* W1 = (const float*)d_in[3];
    const float* b1 = (const float*)d_in[4];
    const float* W2 = (const float*)d_in[5];
    const float* b2 = (const float*)d_in[6];
    const float* W3 = (const float*)d_in[7];
    const float* b3 = (const float*)d_in[8];
    const float* fw1 = (const float*)d_in[9];
    const float* fb1 = (const float*)d_in[10];
    const float* fw2 = (const float*)d_in[11];
    const float* fb2 = (const float*)d_in[12];
    float* out = (float*)d_out;

    const int* src = ei;
    const int* dst = ei + N_EDGES;

    // workspace layout (all chunks multiple of 16 B)
    char* ws = (char*)d_ws;
    int*      cnt_bb      = (int*)ws;                            // 256*392
    int*      btot        = cnt_bb + A_BLOCKS * BSTRIDE;         // 392
    int*      bucket_base = btot + BSTRIDE;                      // 392+8
    unsigned* staging     = (unsigned*)(bucket_base + BSTRIDE + 8);  // E
    int*      row_ptr     = (int*)(staging + N_EDGES);           // N+4
    float*    dis         = (float*)(row_ptr + N_NODES + 4);     // N
    int*      col         = (int*)(dis + N_NODES);               // E
    int*      bounds      = col + N_EDGES;                       // G+1 (+pad)
    bfu*      wpack1      = (bfu*)(bounds + N_GRAPHS + 8);       // 32768 bfu (K=256)
    bfu*      wpack2      = wpack1 + 32768;                      // 16384 bfu (K=128)
    bfu*      wpack3      = wpack2 + 16384;                      // 16384 bfu
    u8*       bufT8       = (u8*)(wpack3 + 16384);               // N*128 fp8 (t1/t2/t3)
    bfu*      bufH        = (bfu*)(bufT8 + (long)N_NODES * 128); // N*128 bf16 (h1/h2/h3)

    // ---- CSR build (counting sort) + merged wpack/bounds ----
    k_hist<<<A_BLOCKS, 256, 0, stream>>>(dst, cnt_bb);
    k_scan_blocks<<<NB_BUCKETS, 256, 0, stream>>>(cnt_bb, btot);
    k_scan_buckets<<<1, 512, 0, stream>>>(btot, bucket_base);
    k_stage<<<A_BLOCKS, 256, 0, stream>>>(src, dst, cnt_bb, bucket_base, staging);
    k_bucket<<<NB_BUCKETS, 256, 0, stream>>>(staging, bucket_base, row_ptr, dis, col);
    k_misc<<<36, 256, 0, stream>>>(W1, W2, W3, wpack1, wpack2, wpack3, batch, bounds);

    const int mm1Grid = (N_NODES + 63) / 64;      // 1563
    const int mm2Grid = (N_NODES + 63) / 64;      // 1563
    const int aggGrid = (N_NODES + 7) / 8;        // 12500

    // layer 1: t1(fp8) = (x @ W1) * dis ; h1(bf16) = relu(dis*gather(t1)+b1)
    k_mm1<<<mm1Grid, 256, 0, stream>>>(x, wpack1, dis, bufT8, N_NODES);
    k_agg8<<<aggGrid, 256, 0, stream>>>(row_ptr, col, dis, bufT8, b1, bufH);
    // layer 2: t2(fp8) = (h1 @ W2) * dis ; h2 = relu(dis*gather(t2)+b2)
    k_mm2<<<mm2Grid, 256, 0, stream>>>(bufH, wpack2, dis, bufT8, N_NODES);
    k_agg8<<<aggGrid, 256, 0, stream>>>(row_ptr, col, dis, bufT8, b2, bufH);
    // layer 3: t3(fp8) = (h2 @ W3) * dis ; h3 = relu(dis*gather(t3)+b3)
    k_mm2<<<mm2Grid, 256, 0, stream>>>(bufH, wpack3, dis, bufT8, N_NODES);
    k_agg8<<<aggGrid, 256, 0, stream>>>(row_ptr, col, dis, bufT8, b3, bufH);

    // fused pool + head
    k_pool_head<<<N_GRAPHS, 128, 0, stream>>>(bounds, bufH, fw1, fb1, fw2, fb2, out);
}

// Round 14
// 305.129 us; speedup vs baseline: 1.3279x; 1.0005x over previous
//
#include <hip/hip_runtime.h>
#include <hip/hip_bf16.h>
#include <math.h>

#define N_NODES 100000
#define N_EDGES 1600000
#define F_IN 256
#define H_DIM 128
#define N_GRAPHS 1000

#define NB_BUCKETS ((N_NODES + 255) >> 8)   // 391 buckets of 256 nodes
#define BSTRIDE 392
#define A_BLOCKS 256
#define EPB (N_EDGES / A_BLOCKS)            // 6250 edges per block (exact)

typedef unsigned short bfu;  // bf16 bit pattern
typedef unsigned char u8;
typedef short short8 __attribute__((ext_vector_type(8)));   // 8 bf16 = 4 VGPR
typedef float f32x4 __attribute__((ext_vector_type(4)));    // MFMA accum
typedef float f32x2 __attribute__((ext_vector_type(2)));

__device__ __forceinline__ float b2f(unsigned u) {
    union { unsigned int i; float f; } v;
    v.i = u << 16;
    return v.f;
}
__device__ __forceinline__ bfu f2b(float f) {
    __hip_bfloat16 h = __float2bfloat16(f);  // RNE
    return *reinterpret_cast<bfu*>(&h);
}
// 4 f32 -> 4 fp8(e4m3) bytes packed in a dword (HW cvt, RNE+sat)
__device__ __forceinline__ unsigned pk4_fp8(float v0, float v1, float v2, float v3) {
    int r = __builtin_amdgcn_cvt_pk_fp8_f32(v0, v1, 0, false);
    r = __builtin_amdgcn_cvt_pk_fp8_f32(v2, v3, r, true);
    return (unsigned)r;
}
// accumulate 4 fp8 (one dword) into a[0..3]
__device__ __forceinline__ void acc4_fp8(float* a, unsigned v) {
    f32x2 p;
    p = __builtin_amdgcn_cvt_pk_f32_fp8((int)v, false); a[0] += p.x; a[1] += p.y;
    p = __builtin_amdgcn_cvt_pk_f32_fp8((int)v, true);  a[2] += p.x; a[3] += p.y;
}

// ---------------- CSR build: bucketed counting sort ----------------
__global__ __launch_bounds__(256) void k_hist(const int* __restrict__ dst,
                                              int* __restrict__ cnt_bb) {
    __shared__ int h[BSTRIDE];
    const int t = threadIdx.x;
    for (int i = t; i < BSTRIDE; i += 256) h[i] = 0;
    __syncthreads();
    const int base = blockIdx.x * EPB;
    for (int i = t; i < EPB; i += 256) atomicAdd(&h[dst[base + i] >> 8], 1);
    __syncthreads();
    for (int i = t; i < NB_BUCKETS; i += 256) cnt_bb[blockIdx.x * BSTRIDE + i] = h[i];
}

__global__ __launch_bounds__(256) void k_scan_blocks(int* __restrict__ cnt_bb,
                                                     int* __restrict__ btot) {
    __shared__ int s[256];
    const int t = threadIdx.x;
    const int b = blockIdx.x;
    int v = cnt_bb[t * BSTRIDE + b];
    s[t] = v;
    __syncthreads();
    for (int off = 1; off < 256; off <<= 1) {
        int u = (t >= off) ? s[t - off] : 0;
        __syncthreads();
        s[t] += u;
        __syncthreads();
    }
    cnt_bb[t * BSTRIDE + b] = s[t] - v;
    if (t == 255) btot[b] = s[255];
}

__global__ __launch_bounds__(512) void k_scan_buckets(const int* __restrict__ btot,
                                                      int* __restrict__ bucket_base) {
    __shared__ int s[512];
    const int t = threadIdx.x;
    int v = (t < NB_BUCKETS) ? btot[t] : 0;
    s[t] = v;
    __syncthreads();
    for (int off = 1; off < 512; off <<= 1) {
        int u = (t >= off) ? s[t - off] : 0;
        __syncthreads();
        s[t] += u;
        __syncthreads();
    }
    if (t < NB_BUCKETS) bucket_base[t] = s[t] - v;
    if (t == 0) bucket_base[NB_BUCKETS] = N_EDGES;
}

__global__ __launch_bounds__(256) void k_stage(const int* __restrict__ src,
                                               const int* __restrict__ dst,
                                               const int* __restrict__ cnt_bb,
                                               const int* __restrict__ bucket_base,
                                               unsigned* __restrict__ staging) {
    __shared__ int cur[BSTRIDE];
    const int t = threadIdx.x;
    const int blk = blockIdx.x;
    for (int i = t; i < NB_BUCKETS; i += 256)
        cur[i] = bucket_base[i] + cnt_bb[blk * BSTRIDE + i];
    __syncthreads();
    const int base = blk * EPB;
    for (int i = t; i < EPB; i += 256) {
        int d = dst[base + i];
        int s = src[base + i];
        int b = d >> 8;
        int pos = atomicAdd(&cur[b], 1);
        staging[pos] = (unsigned)s | ((unsigned)(d & 255) << 24);
    }
}

__global__ __launch_bounds__(256) void k_bucket(const unsigned* __restrict__ staging,
                                                const int* __restrict__ bucket_base,
                                                int* __restrict__ row_ptr,
                                                float* __restrict__ dis,
                                                int* __restrict__ col) {
    __shared__ int h[256];
    __shared__ int sc[256];
    __shared__ int cur[256];
    const int t = threadIdx.x;
    const int b = blockIdx.x;
    const int s0 = bucket_base[b];
    const int ne = bucket_base[b + 1] - s0;
    h[t] = 0;
    __syncthreads();
    for (int i = t; i < ne; i += 256) atomicAdd(&h[staging[s0 + i] >> 24], 1);
    __syncthreads();
    int myc = h[t];
    sc[t] = myc;
    __syncthreads();
    for (int off = 1; off < 256; off <<= 1) {
        int u = (t >= off) ? sc[t - off] : 0;
        __syncthreads();
        sc[t] += u;
        __syncthreads();
    }
    int excl = sc[t] - myc;
    int node = b * 256 + t;
    if (node <= N_NODES) row_ptr[node] = s0 + excl;
    if (node < N_NODES) dis[node] = rsqrtf((float)(myc + 1));
    cur[t] = s0 + excl;
    __syncthreads();
    for (int i = t; i < ne; i += 256) {
        unsigned u = staging[s0 + i];
        int pos = atomicAdd(&cur[u >> 24], 1);
        col[pos] = (int)(u & 0xFFFFFFu);
    }
}

// ---------------- merged: W pre-packs + graph bounds (one launch) ----------------
__device__ __forceinline__ void wpack_one(const float* __restrict__ W,
                                          bfu* __restrict__ Wp, int u) {
    int lane = u & 63;
    int nf = (u >> 6) & 7;
    int ks = u >> 9;
    int k = ks * 32 + (lane >> 4) * 8;
    int n = nf * 16 + (lane & 15);
    bfu o[8];
#pragma unroll
    for (int j = 0; j < 8; ++j) o[j] = f2b(W[(k + j) * 128 + n]);
    uint4 pk;
    pk.x = (unsigned)o[0] | ((unsigned)o[1] << 16);
    pk.y = (unsigned)o[2] | ((unsigned)o[3] << 16);
    pk.z = (unsigned)o[4] | ((unsigned)o[5] << 16);
    pk.w = (unsigned)o[6] | ((unsigned)o[7] << 16);
    *(uint4*)&Wp[u * 8] = pk;
}

__global__ __launch_bounds__(256) void k_misc(const float* __restrict__ W1,
                                              const float* __restrict__ W2,
                                              const float* __restrict__ W3,
                                              bfu* __restrict__ wp1, bfu* __restrict__ wp2,
                                              bfu* __restrict__ wp3,
                                              const int* __restrict__ batch,
                                              int* __restrict__ bounds) {
    const int b = blockIdx.x, t = threadIdx.x;
    if (b < 16) {
        wpack_one(W1, wp1, b * 256 + t);
    } else if (b < 24) {
        wpack_one(W2, wp2, (b - 16) * 256 + t);
    } else if (b < 32) {
        wpack_one(W3, wp3, (b - 24) * 256 + t);
    } else {
        int g = (b - 32) * 256 + t;
        if (g <= N_GRAPHS) {
            int lo = 0, hi = N_NODES;
            while (lo < hi) {
                int mid = (lo + hi) >> 1;
                if (batch[mid] < g) lo = mid + 1; else hi = mid;
            }
            bounds[g] = lo;
        }
    }
}

// ---------------- mm1: direct-to-register; all 16 A-loads pinned before compute ----------------
__global__ __launch_bounds__(256, 2) void k_mm1(const float* __restrict__ A,
                                                const bfu* __restrict__ Wp,
                                                const float* __restrict__ dis,
                                                u8* __restrict__ C8, int M) {
    const int t = threadIdx.x;
    const int w = t >> 6, l = t & 63, l15 = l & 15, lhi = l >> 4;
    const int row = blockIdx.x * 64 + w * 16 + l15;
    const int rowc = row < M ? row : M - 1;
    const float* ap = A + (long)rowc * 256 + lhi * 8;

    float4 va[8][2];
#pragma unroll
    for (int ks = 0; ks < 8; ++ks) {
        va[ks][0] = *(const float4*)(ap + ks * 32);
        va[ks][1] = *(const float4*)(ap + ks * 32 + 4);
    }
    // Pin: all 16 global_load_dwordx4 must issue before anything below.
    __builtin_amdgcn_sched_barrier(0);

    f32x4 acc[8];
#pragma unroll
    for (int nf = 0; nf < 8; ++nf) acc[nf] = (f32x4)0.0f;

#pragma unroll
    for (int ks = 0; ks < 8; ++ks) {
        unsigned p0 = (unsigned)f2b(va[ks][0].x) | ((unsigned)f2b(va[ks][0].y) << 16);
        unsigned p1 = (unsigned)f2b(va[ks][0].z) | ((unsigned)f2b(va[ks][0].w) << 16);
        unsigned p2 = (unsigned)f2b(va[ks][1].x) | ((unsigned)f2b(va[ks][1].y) << 16);
        unsigned p3 = (unsigned)f2b(va[ks][1].z) | ((unsigned)f2b(va[ks][1].w) << 16);
        uint4 afu = make_uint4(p0, p1, p2, p3);
        short8 af = *(short8*)&afu;
        const bfu* wp = Wp + ((long)(ks * 8) * 64 + l) * 8;
#pragma unroll
        for (int nf = 0; nf < 8; ++nf) {
            short8 wf = *(const short8*)(wp + (long)nf * 64 * 8);
            acc[nf] = __builtin_amdgcn_mfma_f32_16x16x32_bf16(wf, af, acc[nf], 0, 0, 0);
        }
    }
    if (row < M) {
        float sc = dis[row];
        int nb0 = lhi * 4;
#pragma unroll
        for (int nf = 0; nf < 8; ++nf) {
            unsigned pk = pk4_fp8(acc[nf][0] * sc, acc[nf][1] * sc,
                                  acc[nf][2] * sc, acc[nf][3] * sc);
            *(unsigned*)&C8[(long)row * 128 + nf * 16 + nb0] = pk;
        }
    }
}

// ---------------- agg8: fp8 t' gather -> bf16 h (8 nodes/block, 32 lanes/node, 8-edge unroll) ----------------
__global__ __launch_bounds__(256) void k_agg8(const int* __restrict__ row_ptr,
                                              const int* __restrict__ col,
                                              const float* __restrict__ dis,
                                              const u8* __restrict__ t8,
                                              const float* __restrict__ b,
                                              bfu* __restrict__ h) {
    const int t = threadIdx.x;
    const int node = blockIdx.x * 8 + (t >> 5);
    const int lane = t & 31;
    if (node >= N_NODES) return;
    const int q = lane << 2;  // 4 channels per lane (4 fp8 bytes)

    const u8* tp = t8 + q;
    float a[4] = {0.f, 0.f, 0.f, 0.f};
    acc4_fp8(a, *(const unsigned*)&tp[(long)node * 128]);  // self term

    int e = row_ptr[node];
    const int end = row_ptr[node + 1];
    for (; e + 7 < end; e += 8) {
        unsigned v[8];
#pragma unroll
        for (int j = 0; j < 8; ++j) v[j] = *(const unsigned*)&tp[(long)col[e + j] * 128];
#pragma unroll
        for (int j = 0; j < 8; ++j) acc4_fp8(a, v[j]);
    }
    for (; e + 3 < end; e += 4) {
        unsigned v0 = *(const unsigned*)&tp[(long)col[e] * 128];
        unsigned v1 = *(const unsigned*)&tp[(long)col[e + 1] * 128];
        unsigned v2 = *(const unsigned*)&tp[(long)col[e + 2] * 128];
        unsigned v3 = *(const unsigned*)&tp[(long)col[e + 3] * 128];
        acc4_fp8(a, v0); acc4_fp8(a, v1); acc4_fp8(a, v2); acc4_fp8(a, v3);
    }
    for (; e < end; ++e)
        acc4_fp8(a, *(const unsigned*)&tp[(long)col[e] * 128]);

    const float dn = dis[node];
    float4 bb = *(const float4*)&b[q];
    float o0 = fmaxf(a[0] * dn + bb.x, 0.0f);
    float o1 = fmaxf(a[1] * dn + bb.y, 0.0f);
    float o2 = fmaxf(a[2] * dn + bb.z, 0.0f);
    float o3 = fmaxf(a[3] * dn + bb.w, 0.0f);
    uint2 pk;
    pk.x = (unsigned)f2b(o0) | ((unsigned)f2b(o1) << 16);
    pk.y = (unsigned)f2b(o2) | ((unsigned)f2b(o3) << 16);
    *(uint2*)&h[(long)node * 128 + q] = pk;
}

// ---------------- mm2: bf16 h (streaming) @ W -> fp8 t' (dbuf LDS + reg prefetch) ----------------
__global__ __launch_bounds__(256) void k_mm2(const bfu* __restrict__ A,
                                             const bfu* __restrict__ Wp,
                                             const float* __restrict__ dis,
                                             u8* __restrict__ C8, int M) {
    __shared__ bfu As[2][64 * 40];
    const int t = threadIdx.x;
    const int w = t >> 6;
    const int l = t & 63;
    const int l15 = l & 15;
    const int lhi = l >> 4;
    const int row0 = blockIdx.x * 64;

    f32x4 acc[8];
#pragma unroll
    for (int nf = 0; nf < 8; ++nf) acc[nf] = (f32x4)0.0f;

    uint4 pb = make_uint4(0u, 0u, 0u, 0u);
    {
        int r = t >> 2, s = t & 3;
        if (row0 + r < M) pb = *(const uint4*)&A[(long)(row0 + r) * 128 + s * 8];
    }

    int buf = 0;
#pragma unroll
    for (int ks = 0; ks < 4; ++ks) {
        *(uint4*)&As[buf][(t >> 2) * 40 + (t & 3) * 8] = pb;
        if (ks + 1 < 4) {
            const int k0n = (ks + 1) * 32;
            int r = t >> 2, s = t & 3;
            pb = make_uint4(0u, 0u, 0u, 0u);
            if (row0 + r < M) pb = *(const uint4*)&A[(long)(row0 + r) * 128 + k0n + s * 8];
        }
        __syncthreads();
        short8 af = *(const short8*)&As[buf][(w * 16 + l15) * 40 + lhi * 8];
        const bfu* wp = Wp + ((long)(ks * 8) * 64 + l) * 8;
#pragma unroll
        for (int nf = 0; nf < 8; ++nf) {
            short8 wf = *(const short8*)(wp + (long)nf * 64 * 8);
            acc[nf] = __builtin_amdgcn_mfma_f32_16x16x32_bf16(wf, af, acc[nf], 0, 0, 0);
        }
        if (ks + 1 < 4) __syncthreads();
        buf ^= 1;
    }
    int row = row0 + w * 16 + l15;
    if (row < M) {
        float sc = dis[row];
        int nb0 = lhi * 4;
#pragma unroll
        for (int nf = 0; nf < 8; ++nf) {
            unsigned pko = pk4_fp8(acc[nf][0] * sc, acc[nf][1] * sc,
                                   acc[nf][2] * sc, acc[nf][3] * sc);
            *(unsigned*)&C8[(long)row * 128 + nf * 16 + nb0] = pko;
        }
    }
}

// ---------------- fused pool (mean over segment; h already relu'd) + MLP head ----------------
__global__ __launch_bounds__(128) void k_pool_head(const int* __restrict__ bounds,
                                                   const bfu* __restrict__ h,
                                                   const float* __restrict__ fw1, const float* __restrict__ fb1,
                                                   const float* __restrict__ fw2, const float* __restrict__ fb2,
                                                   float* __restrict__ out) {
    const int g = blockIdx.x;
    const int t = threadIdx.x;
    const int s = bounds[g], e = bounds[g + 1];
    float sum = 0.0f;
    int n = s;
    for (; n + 1 < e; n += 2) {
        sum += b2f(h[(long)n * 128 + t]);
        sum += b2f(h[(long)(n + 1) * 128 + t]);
    }
    if (n < e) sum += b2f(h[(long)n * 128 + t]);

    __shared__ float sg[128];
    __shared__ float sh[32];
    float inv = 1.0f / fmaxf((float)(e - s), 1.0f);
    sg[t] = sum * inv;
    __syncthreads();
    if (t < 32) {
        float a = fb1[t];
#pragma unroll 8
        for (int k = 0; k < 128; ++k) a += sg[k] * fw1[k * 32 + t];
        sh[t] = fmaxf(a, 0.0f);
    }
    __syncthreads();
    if (t == 0) {
        float l0 = fb2[0], l1 = fb2[1];
        for (int k = 0; k < 32; ++k) {
            l0 += sh[k] * fw2[k * 2];
            l1 += sh[k] * fw2[k * 2 + 1];
        }
        float m = fmaxf(l0, l1);
        float lse = m + logf(expf(l0 - m) + expf(l1 - m));
        out[g * 2 + 0] = l0 - lse;
        out[g * 2 + 1] = l1 - lse;
    }
}

extern "C" void kernel_launch(void* const* d_in, const int* in_sizes, int n_in,
                              void* d_out, int out_size, void* d_ws, size_t ws_size,
                              hipStream_t stream) {
    const float* x  = (const float*)d_in[0];
    const int* ei   = (const int*)d_in[1];
    const int* batch = (const int*)d_in[2];
    const float* W1 = (const float*)d_in[3];
    const float* b1 = (const float*)d_in[4];
    const float* W2 = (const float*)d_in[5];
    const float* b2 = (const float*)d_in[6];
    const float* W3 = (const float*)d_in[7];
    const float* b3 = (const float*)d_in[8];
    const float* fw1 = (const float*)d_in[9];
    const float* fb1 = (const float*)d_in[10];
    const float* fw2 = (const float*)d_in[11];
    const float* fb2 = (const float*)d_in[12];
    float* out = (float*)d_out;

    const int* src = ei;
    const int* dst = ei + N_EDGES;

    // workspace layout (all chunks multiple of 16 B)
    char* ws = (char*)d_ws;
    int*      cnt_bb      = (int*)ws;                            // 256*392
    int*      btot        = cnt_bb + A_BLOCKS * BSTRIDE;         // 392
    int*      bucket_base = btot + BSTRIDE;                      // 392+8
    unsigned* staging     = (unsigned*)(bucket_base + BSTRIDE + 8);  // E
    int*      row_ptr     = (int*)(staging + N_EDGES);           // N+4
    float*    dis         = (float*)(row_ptr + N_NODES + 4);     // N
    int*      col         = (int*)(dis + N_NODES);               // E
    int*      bounds      = col + N_EDGES;                       // G+1 (+pad)
    bfu*      wpack1      = (bfu*)(bounds + N_GRAPHS + 8);       // 32768 bfu (K=256)
    bfu*      wpack2      = wpack1 + 32768;                      // 16384 bfu (K=128)
    bfu*      wpack3      = wpack2 + 16384;                      // 16384 bfu
    u8*       bufT8       = (u8*)(wpack3 + 16384);               // N*128 fp8 (t1/t2/t3)
    bfu*      bufH        = (bfu*)(bufT8 + (long)N_NODES * 128); // N*128 bf16 (h1/h2/h3)

    // ---- CSR build (counting sort) + merged wpack/bounds ----
    k_hist<<<A_BLOCKS, 256, 0, stream>>>(dst, cnt_bb);
    k_scan_blocks<<<NB_BUCKETS, 256, 0, stream>>>(cnt_bb, btot);
    k_scan_buckets<<<1, 512, 0, stream>>>(btot, bucket_base);
    k_stage<<<A_BLOCKS, 256, 0, stream>>>(src, dst, cnt_bb, bucket_base, staging);
    k_bucket<<<NB_BUCKETS, 256, 0, stream>>>(staging, bucket_base, row_ptr, dis, col);
    k_misc<<<36, 256, 0, stream>>>(W1, W2, W3, wpack1, wpack2, wpack3, batch, bounds);

    const int mm1Grid = (N_NODES + 63) / 64;      // 1563
    const int mm2Grid = (N_NODES + 63) / 64;      // 1563
    const int aggGrid = (N_NODES + 7) / 8;        // 12500

    // layer 1: t1(fp8) = (x @ W1) * dis ; h1(bf16) = relu(dis*gather(t1)+b1)
    k_mm1<<<mm1Grid, 256, 0, stream>>>(x, wpack1, dis, bufT8, N_NODES);
    k_agg8<<<aggGrid, 256, 0, stream>>>(row_ptr, col, dis, bufT8, b1, bufH);
    // layer 2: t2(fp8) = (h1 @ W2) * dis ; h2 = relu(dis*gather(t2)+b2)
    k_mm2<<<mm2Grid, 256, 0, stream>>>(bufH, wpack2, dis, bufT8, N_NODES);
    k_agg8<<<aggGrid, 256, 0, stream>>>(row_ptr, col, dis, bufT8, b2, bufH);
    // layer 3: t3(fp8) = (h2 @ W3) * dis ; h3 = relu(dis*gather(t3)+b3)
    k_mm2<<<mm2Grid, 256, 0, stream>>>(bufH, wpack3, dis, bufT8, N_NODES);
    k_agg8<<<aggGrid, 256, 0, stream>>>(row_ptr, col, dis, bufT8, b3, bufH);

    // fused pool + head
    k_pool_head<<<N_GRAPHS, 128, 0, stream>>>(bounds, bufH, fw1, fb1, fw2, fb2, out);
}

// Round 15
// 302.174 us; speedup vs baseline: 1.3409x; 1.0098x over previous
//
#include <hip/hip_runtime.h>
#include <hip/hip_bf16.h>
#include <math.h>

#define N_NODES 100000
#define N_EDGES 1600000
#define F_IN 256
#define H_DIM 128
#define N_GRAPHS 1000

#define NB_BUCKETS ((N_NODES + 255) >> 8)   // 391 buckets of 256 nodes
#define BSTRIDE 392
#define A_BLOCKS 256
#define EPB (N_EDGES / A_BLOCKS)            // 6250 edges per block (exact)

typedef unsigned short bfu;  // bf16 bit pattern
typedef unsigned char u8;
typedef short short8 __attribute__((ext_vector_type(8)));   // 8 bf16 = 4 VGPR
typedef float f32x4 __attribute__((ext_vector_type(4)));    // MFMA accum
typedef float f32x2 __attribute__((ext_vector_type(2)));

__device__ __forceinline__ float b2f(unsigned u) {
    union { unsigned int i; float f; } v;
    v.i = u << 16;
    return v.f;
}
__device__ __forceinline__ bfu f2b(float f) {
    __hip_bfloat16 h = __float2bfloat16(f);  // RNE
    return *reinterpret_cast<bfu*>(&h);
}
// 4 f32 -> 4 fp8(e4m3) bytes packed in a dword (HW cvt, RNE+sat)
__device__ __forceinline__ unsigned pk4_fp8(float v0, float v1, float v2, float v3) {
    int r = __builtin_amdgcn_cvt_pk_fp8_f32(v0, v1, 0, false);
    r = __builtin_amdgcn_cvt_pk_fp8_f32(v2, v3, r, true);
    return (unsigned)r;
}
// accumulate 4 fp8 (one dword) into a[0..3]
__device__ __forceinline__ void acc4_fp8(float* a, unsigned v) {
    f32x2 p;
    p = __builtin_amdgcn_cvt_pk_f32_fp8((int)v, false); a[0] += p.x; a[1] += p.y;
    p = __builtin_amdgcn_cvt_pk_f32_fp8((int)v, true);  a[2] += p.x; a[3] += p.y;
}
// 8 fp8 (uint2) -> 8 bf16 (uint4), exact (e4m3 subset of bf16)
__device__ __forceinline__ uint4 fp8x8_to_bf16x8(uint2 v) {
    f32x2 p0 = __builtin_amdgcn_cvt_pk_f32_fp8((int)v.x, false);
    f32x2 p1 = __builtin_amdgcn_cvt_pk_f32_fp8((int)v.x, true);
    f32x2 p2 = __builtin_amdgcn_cvt_pk_f32_fp8((int)v.y, false);
    f32x2 p3 = __builtin_amdgcn_cvt_pk_f32_fp8((int)v.y, true);
    uint4 o;
    o.x = (unsigned)f2b(p0.x) | ((unsigned)f2b(p0.y) << 16);
    o.y = (unsigned)f2b(p1.x) | ((unsigned)f2b(p1.y) << 16);
    o.z = (unsigned)f2b(p2.x) | ((unsigned)f2b(p2.y) << 16);
    o.w = (unsigned)f2b(p3.x) | ((unsigned)f2b(p3.y) << 16);
    return o;
}

// ---------------- CSR build: bucketed counting sort ----------------
__global__ __launch_bounds__(256) void k_hist(const int* __restrict__ dst,
                                              int* __restrict__ cnt_bb) {
    __shared__ int h[BSTRIDE];
    const int t = threadIdx.x;
    for (int i = t; i < BSTRIDE; i += 256) h[i] = 0;
    __syncthreads();
    const int base = blockIdx.x * EPB;
    for (int i = t; i < EPB; i += 256) atomicAdd(&h[dst[base + i] >> 8], 1);
    __syncthreads();
    for (int i = t; i < NB_BUCKETS; i += 256) cnt_bb[blockIdx.x * BSTRIDE + i] = h[i];
}

__global__ __launch_bounds__(256) void k_scan_blocks(int* __restrict__ cnt_bb,
                                                     int* __restrict__ btot) {
    __shared__ int s[256];
    const int t = threadIdx.x;
    const int b = blockIdx.x;
    int v = cnt_bb[t * BSTRIDE + b];
    s[t] = v;
    __syncthreads();
    for (int off = 1; off < 256; off <<= 1) {
        int u = (t >= off) ? s[t - off] : 0;
        __syncthreads();
        s[t] += u;
        __syncthreads();
    }
    cnt_bb[t * BSTRIDE + b] = s[t] - v;
    if (t == 255) btot[b] = s[255];
}

__global__ __launch_bounds__(256) void k_stage(const int* __restrict__ src,
                                               const int* __restrict__ dst,
                                               const int* __restrict__ cnt_bb,
                                               const int* __restrict__ bucket_base,
                                               unsigned* __restrict__ staging) {
    __shared__ int cur[BSTRIDE];
    const int t = threadIdx.x;
    const int blk = blockIdx.x;
    for (int i = t; i < NB_BUCKETS; i += 256)
        cur[i] = bucket_base[i] + cnt_bb[blk * BSTRIDE + i];
    __syncthreads();
    const int base = blk * EPB;
    for (int i = t; i < EPB; i += 256) {
        int d = dst[base + i];
        int s = src[base + i];
        int b = d >> 8;
        int pos = atomicAdd(&cur[b], 1);
        staging[pos] = (unsigned)s | ((unsigned)(d & 255) << 24);
    }
}

__global__ __launch_bounds__(256) void k_bucket(const unsigned* __restrict__ staging,
                                                const int* __restrict__ bucket_base,
                                                int* __restrict__ row_ptr,
                                                float* __restrict__ dis,
                                                int* __restrict__ col) {
    __shared__ int h[256];
    __shared__ int sc[256];
    __shared__ int cur[256];
    const int t = threadIdx.x;
    const int b = blockIdx.x;
    const int s0 = bucket_base[b];
    const int ne = bucket_base[b + 1] - s0;
    h[t] = 0;
    __syncthreads();
    for (int i = t; i < ne; i += 256) atomicAdd(&h[staging[s0 + i] >> 24], 1);
    __syncthreads();
    int myc = h[t];
    sc[t] = myc;
    __syncthreads();
    for (int off = 1; off < 256; off <<= 1) {
        int u = (t >= off) ? sc[t - off] : 0;
        __syncthreads();
        sc[t] += u;
        __syncthreads();
    }
    int excl = sc[t] - myc;
    int node = b * 256 + t;
    if (node <= N_NODES) row_ptr[node] = s0 + excl;
    if (node < N_NODES) dis[node] = rsqrtf((float)(myc + 1));
    cur[t] = s0 + excl;
    __syncthreads();
    for (int i = t; i < ne; i += 256) {
        unsigned u = staging[s0 + i];
        int pos = atomicAdd(&cur[u >> 24], 1);
        col[pos] = (int)(u & 0xFFFFFFu);
    }
}

// ---------------- merged: W pre-packs + graph bounds + bucket scan (one launch) ----------------
__device__ __forceinline__ void wpack_one(const float* __restrict__ W,
                                          bfu* __restrict__ Wp, int u) {
    int lane = u & 63;
    int nf = (u >> 6) & 7;
    int ks = u >> 9;
    int k = ks * 32 + (lane >> 4) * 8;
    int n = nf * 16 + (lane & 15);
    bfu o[8];
#pragma unroll
    for (int j = 0; j < 8; ++j) o[j] = f2b(W[(k + j) * 128 + n]);
    uint4 pk;
    pk.x = (unsigned)o[0] | ((unsigned)o[1] << 16);
    pk.y = (unsigned)o[2] | ((unsigned)o[3] << 16);
    pk.z = (unsigned)o[4] | ((unsigned)o[5] << 16);
    pk.w = (unsigned)o[6] | ((unsigned)o[7] << 16);
    *(uint4*)&Wp[u * 8] = pk;
}

__global__ __launch_bounds__(256) void k_misc(const float* __restrict__ W1,
                                              const float* __restrict__ W2,
                                              const float* __restrict__ W3,
                                              bfu* __restrict__ wp1, bfu* __restrict__ wp2,
                                              bfu* __restrict__ wp3,
                                              const int* __restrict__ batch,
                                              int* __restrict__ bounds,
                                              const int* __restrict__ btot,
                                              int* __restrict__ bucket_base) {
    const int b = blockIdx.x, t = threadIdx.x;
    if (b < 16) {
        wpack_one(W1, wp1, b * 256 + t);
    } else if (b < 24) {
        wpack_one(W2, wp2, (b - 16) * 256 + t);
    } else if (b < 32) {
        wpack_one(W3, wp3, (b - 24) * 256 + t);
    } else if (b < 36) {
        int g = (b - 32) * 256 + t;
        if (g <= N_GRAPHS) {
            int lo = 0, hi = N_NODES;
            while (lo < hi) {
                int mid = (lo + hi) >> 1;
                if (batch[mid] < g) lo = mid + 1; else hi = mid;
            }
            bounds[g] = lo;
        }
    } else {
        // exclusive scan of 391 bucket totals (2 elems/thread)
        __shared__ int s[256];
        int g0 = 2 * t, g1 = 2 * t + 1;
        int v0 = (g0 < NB_BUCKETS) ? btot[g0] : 0;
        int v1 = (g1 < NB_BUCKETS) ? btot[g1] : 0;
        int pair = v0 + v1;
        s[t] = pair;
        __syncthreads();
        for (int off = 1; off < 256; off <<= 1) {
            int u = (t >= off) ? s[t - off] : 0;
            __syncthreads();
            s[t] += u;
            __syncthreads();
        }
        int excl = s[t] - pair;
        if (g0 < NB_BUCKETS) bucket_base[g0] = excl;
        if (g1 < NB_BUCKETS) bucket_base[g1] = excl + v0;
        if (t == 0) bucket_base[NB_BUCKETS] = N_EDGES;
    }
}

// ---------------- mm1: depth-4 software-pipelined register rotate ----------------
// 256 thr = 4 waves x 16 rows; circular buf[4][2] bounds live loads at 8 float4 (32 VGPR),
// prefetch of ks+4 issues before consumption of ks -> guaranteed 4-deep pipeline, no barriers.
__global__ __launch_bounds__(256, 2) void k_mm1(const float* __restrict__ A,
                                                const bfu* __restrict__ Wp,
                                                const float* __restrict__ dis,
                                                u8* __restrict__ C8, int M) {
    const int t = threadIdx.x;
    const int w = t >> 6, l = t & 63, l15 = l & 15, lhi = l >> 4;
    const int row = blockIdx.x * 64 + w * 16 + l15;
    const int rowc = row < M ? row : M - 1;   // clamp: no OOB, garbage rows never stored
    const float* ap = A + (long)rowc * 256 + lhi * 8;

    float4 buf[4][2];
#pragma unroll
    for (int i = 0; i < 4; ++i) {
        buf[i][0] = *(const float4*)(ap + i * 32);
        buf[i][1] = *(const float4*)(ap + i * 32 + 4);
    }

    f32x4 acc[8];
#pragma unroll
    for (int nf = 0; nf < 8; ++nf) acc[nf] = (f32x4)0.0f;

#pragma unroll
    for (int ks = 0; ks < 8; ++ks) {
        float4 c0 = buf[ks & 3][0];
        float4 c1 = buf[ks & 3][1];
        if (ks + 4 < 8) {
            buf[ks & 3][0] = *(const float4*)(ap + (ks + 4) * 32);
            buf[ks & 3][1] = *(const float4*)(ap + (ks + 4) * 32 + 4);
        }
        unsigned p0 = (unsigned)f2b(c0.x) | ((unsigned)f2b(c0.y) << 16);
        unsigned p1 = (unsigned)f2b(c0.z) | ((unsigned)f2b(c0.w) << 16);
        unsigned p2 = (unsigned)f2b(c1.x) | ((unsigned)f2b(c1.y) << 16);
        unsigned p3 = (unsigned)f2b(c1.z) | ((unsigned)f2b(c1.w) << 16);
        uint4 afu = make_uint4(p0, p1, p2, p3);
        short8 af = *(short8*)&afu;
        const bfu* wp = Wp + ((long)(ks * 8) * 64 + l) * 8;
#pragma unroll
        for (int nf = 0; nf < 8; ++nf) {
            short8 wf = *(const short8*)(wp + (long)nf * 64 * 8);
            acc[nf] = __builtin_amdgcn_mfma_f32_16x16x32_bf16(wf, af, acc[nf], 0, 0, 0);
        }
    }
    if (row < M) {
        float sc = dis[row];
        int nb0 = lhi * 4;
#pragma unroll
        for (int nf = 0; nf < 8; ++nf) {
            unsigned pk = pk4_fp8(acc[nf][0] * sc, acc[nf][1] * sc,
                                  acc[nf][2] * sc, acc[nf][3] * sc);
            *(unsigned*)&C8[(long)row * 128 + nf * 16 + nb0] = pk;
        }
    }
}

// ---------------- agg8: fp8 t' gather -> h (fp8 for layers 1/2, bf16 for layer 3) ----------------
template <bool OUT_BF16>
__global__ __launch_bounds__(256) void k_agg8(const int* __restrict__ row_ptr,
                                              const int* __restrict__ col,
                                              const float* __restrict__ dis,
                                              const u8* __restrict__ t8,
                                              const float* __restrict__ b,
                                              bfu* __restrict__ h16,
                                              u8* __restrict__ h8) {
    const int t = threadIdx.x;
    const int node = blockIdx.x * 8 + (t >> 5);
    const int lane = t & 31;
    if (node >= N_NODES) return;
    const int q = lane << 2;  // 4 channels per lane (4 fp8 bytes)

    const u8* tp = t8 + q;
    float a[4] = {0.f, 0.f, 0.f, 0.f};
    acc4_fp8(a, *(const unsigned*)&tp[(long)node * 128]);  // self term

    int e = row_ptr[node];
    const int end = row_ptr[node + 1];
    for (; e + 7 < end; e += 8) {
        unsigned v[8];
#pragma unroll
        for (int j = 0; j < 8; ++j) v[j] = *(const unsigned*)&tp[(long)col[e + j] * 128];
#pragma unroll
        for (int j = 0; j < 8; ++j) acc4_fp8(a, v[j]);
    }
    for (; e + 3 < end; e += 4) {
        unsigned v0 = *(const unsigned*)&tp[(long)col[e] * 128];
        unsigned v1 = *(const unsigned*)&tp[(long)col[e + 1] * 128];
        unsigned v2 = *(const unsigned*)&tp[(long)col[e + 2] * 128];
        unsigned v3 = *(const unsigned*)&tp[(long)col[e + 3] * 128];
        acc4_fp8(a, v0); acc4_fp8(a, v1); acc4_fp8(a, v2); acc4_fp8(a, v3);
    }
    for (; e < end; ++e)
        acc4_fp8(a, *(const unsigned*)&tp[(long)col[e] * 128]);

    const float dn = dis[node];
    float4 bb = *(const float4*)&b[q];
    float o0 = fmaxf(a[0] * dn + bb.x, 0.0f);
    float o1 = fmaxf(a[1] * dn + bb.y, 0.0f);
    float o2 = fmaxf(a[2] * dn + bb.z, 0.0f);
    float o3 = fmaxf(a[3] * dn + bb.w, 0.0f);
    if (OUT_BF16) {
        uint2 pk;
        pk.x = (unsigned)f2b(o0) | ((unsigned)f2b(o1) << 16);
        pk.y = (unsigned)f2b(o2) | ((unsigned)f2b(o3) << 16);
        *(uint2*)&h16[(long)node * 128 + q] = pk;
    } else {
        *(unsigned*)&h8[(long)node * 128 + q] = pk4_fp8(o0, o1, o2, o3);
    }
}

// ---------------- mm2: fp8 h (streaming) @ W -> fp8 t' (dbuf LDS + reg prefetch) ----------------
// Staging converts fp8->bf16 (exact: e4m3 subset of bf16); MFMA math unchanged.
__global__ __launch_bounds__(256) void k_mm2(const u8* __restrict__ A8,
                                             const bfu* __restrict__ Wp,
                                             const float* __restrict__ dis,
                                             u8* __restrict__ C8, int M) {
    __shared__ bfu As[2][64 * 40];
    const int t = threadIdx.x;
    const int w = t >> 6;
    const int l = t & 63;
    const int l15 = l & 15;
    const int lhi = l >> 4;
    const int row0 = blockIdx.x * 64;

    f32x4 acc[8];
#pragma unroll
    for (int nf = 0; nf < 8; ++nf) acc[nf] = (f32x4)0.0f;

    uint2 pb = make_uint2(0u, 0u);
    {
        int r = t >> 2, s = t & 3;
        if (row0 + r < M) pb = *(const uint2*)&A8[(long)(row0 + r) * 128 + s * 8];
    }

    int buf = 0;
#pragma unroll
    for (int ks = 0; ks < 4; ++ks) {
        *(uint4*)&As[buf][(t >> 2) * 40 + (t & 3) * 8] = fp8x8_to_bf16x8(pb);
        if (ks + 1 < 4) {
            const int k0n = (ks + 1) * 32;
            int r = t >> 2, s = t & 3;
            pb = make_uint2(0u, 0u);
            if (row0 + r < M) pb = *(const uint2*)&A8[(long)(row0 + r) * 128 + k0n + s * 8];
        }
        __syncthreads();
        short8 af = *(const short8*)&As[buf][(w * 16 + l15) * 40 + lhi * 8];
        const bfu* wp = Wp + ((long)(ks * 8) * 64 + l) * 8;
#pragma unroll
        for (int nf = 0; nf < 8; ++nf) {
            short8 wf = *(const short8*)(wp + (long)nf * 64 * 8);
            acc[nf] = __builtin_amdgcn_mfma_f32_16x16x32_bf16(wf, af, acc[nf], 0, 0, 0);
        }
        if (ks + 1 < 4) __syncthreads();
        buf ^= 1;
    }
    int row = row0 + w * 16 + l15;
    if (row < M) {
        float sc = dis[row];
        int nb0 = lhi * 4;
#pragma unroll
        for (int nf = 0; nf < 8; ++nf) {
            unsigned pko = pk4_fp8(acc[nf][0] * sc, acc[nf][1] * sc,
                                   acc[nf][2] * sc, acc[nf][3] * sc);
            *(unsigned*)&C8[(long)row * 128 + nf * 16 + nb0] = pko;
        }
    }
}

// ---------------- fused pool (mean over segment; h already relu'd) + MLP head ----------------
__global__ __launch_bounds__(128) void k_pool_head(const int* __restrict__ bounds,
                                                   const bfu* __restrict__ h,
                                                   const float* __restrict__ fw1, const float* __restrict__ fb1,
                                                   const float* __restrict__ fw2, const float* __restrict__ fb2,
                                                   float* __restrict__ out) {
    const int g = blockIdx.x;
    const int t = threadIdx.x;
    const int s = bounds[g], e = bounds[g + 1];
    float sum = 0.0f;
    int n = s;
    for (; n + 1 < e; n += 2) {
        sum += b2f(h[(long)n * 128 + t]);
        sum += b2f(h[(long)(n + 1) * 128 + t]);
    }
    if (n < e) sum += b2f(h[(long)n * 128 + t]);

    __shared__ float sg[128];
    __shared__ float sh[32];
    float inv = 1.0f / fmaxf((float)(e - s), 1.0f);
    sg[t] = sum * inv;
    __syncthreads();
    if (t < 32) {
        float a = fb1[t];
#pragma unroll 8
        for (int k = 0; k < 128; ++k) a += sg[k] * fw1[k * 32 + t];
        sh[t] = fmaxf(a, 0.0f);
    }
    __syncthreads();
    if (t == 0) {
        float l0 = fb2[0], l1 = fb2[1];
        for (int k = 0; k < 32; ++k) {
            l0 += sh[k] * fw2[k * 2];
            l1 += sh[k] * fw2[k * 2 + 1];
        }
        float m = fmaxf(l0, l1);
        float lse = m + logf(expf(l0 - m) + expf(l1 - m));
        out[g * 2 + 0] = l0 - lse;
        out[g * 2 + 1] = l1 - lse;
    }
}

extern "C" void kernel_launch(void* const* d_in, const int* in_sizes, int n_in,
                              void* d_out, int out_size, void* d_ws, size_t ws_size,
                              hipStream_t stream) {
    const float* x  = (const float*)d_in[0];
    const int* ei   = (const int*)d_in[1];
    const int* batch = (const int*)d_in[2];
    const float* W1 = (const float*)d_in[3];
    const float* b1 = (const float*)d_in[4];
    const float* W2 = (const float*)d_in[5];
    const float* b2 = (const float*)d_in[6];
    const float* W3 = (const float*)d_in[7];
    const float* b3 = (const float*)d_in[8];
    const float* fw1 = (const float*)d_in[9];
    const float* fb1 = (const float*)d_in[10];
    const float* fw2 = (const float*)d_in[11];
    const float* fb2 = (const float*)d_in[12];
    float* out = (float*)d_out;

    const int* src = ei;
    const int* dst = ei + N_EDGES;

    // workspace layout (all chunks multiple of 16 B)
    char* ws = (char*)d_ws;
    int*      cnt_bb      = (int*)ws;                            // 256*392
    int*      btot        = cnt_bb + A_BLOCKS * BSTRIDE;         // 392
    int*      bucket_base = btot + BSTRIDE;                      // 392+8
    unsigned* staging     = (unsigned*)(bucket_base + BSTRIDE + 8);  // E
    int*      row_ptr     = (int*)(staging + N_EDGES);           // N+4
    float*    dis         = (float*)(row_ptr + N_NODES + 4);     // N
    int*      col         = (int*)(dis + N_NODES);               // E
    int*      bounds      = col + N_EDGES;                       // G+1 (+pad)
    bfu*      wpack1      = (bfu*)(bounds + N_GRAPHS + 8);       // 32768 bfu (K=256)
    bfu*      wpack2      = wpack1 + 32768;                      // 16384 bfu (K=128)
    bfu*      wpack3      = wpack2 + 16384;                      // 16384 bfu
    u8*       bufT8       = (u8*)(wpack3 + 16384);               // N*128 fp8 (t1/t2/t3)
    u8*       bufH8       = bufT8 + (long)N_NODES * 128;         // N*128 fp8 (h1/h2)
    bfu*      bufH        = (bfu*)(bufH8 + (long)N_NODES * 128); // N*128 bf16 (h3)

    // ---- CSR build (counting sort) + merged wpack/bounds/bucket-scan ----
    k_hist<<<A_BLOCKS, 256, 0, stream>>>(dst, cnt_bb);
    k_scan_blocks<<<NB_BUCKETS, 256, 0, stream>>>(cnt_bb, btot);
    k_misc<<<37, 256, 0, stream>>>(W1, W2, W3, wpack1, wpack2, wpack3, batch, bounds,
                                   btot, bucket_base);
    k_stage<<<A_BLOCKS, 256, 0, stream>>>(src, dst, cnt_bb, bucket_base, staging);
    k_bucket<<<NB_BUCKETS, 256, 0, stream>>>(staging, bucket_base, row_ptr, dis, col);

    const int mm1Grid = (N_NODES + 63) / 64;      // 1563
    const int mm2Grid = (N_NODES + 63) / 64;      // 1563
    const int aggGrid = (N_NODES + 7) / 8;        // 12500

    // layer 1: t1(fp8) = (x @ W1) * dis ; h1(fp8) = relu(dis*gather(t1)+b1)
    k_mm1<<<mm1Grid, 256, 0, stream>>>(x, wpack1, dis, bufT8, N_NODES);
    k_agg8<false><<<aggGrid, 256, 0, stream>>>(row_ptr, col, dis, bufT8, b1, nullptr, bufH8);
    // layer 2: t2(fp8) = (h1 @ W2) * dis ; h2(fp8) = relu(dis*gather(t2)+b2)
    k_mm2<<<mm2Grid, 256, 0, stream>>>(bufH8, wpack2, dis, bufT8, N_NODES);
    k_agg8<false><<<aggGrid, 256, 0, stream>>>(row_ptr, col, dis, bufT8, b2, nullptr, bufH8);
    // layer 3: t3(fp8) = (h2 @ W3) * dis ; h3(bf16) = relu(dis*gather(t3)+b3)
    k_mm2<<<mm2Grid, 256, 0, stream>>>(bufH8, wpack3, dis, bufT8, N_NODES);
    k_agg8<true><<<aggGrid, 256, 0, stream>>>(row_ptr, col, dis, bufT8, b3, bufH, nullptr);

    // fused pool + head
    k_pool_head<<<N_GRAPHS, 128, 0, stream>>>(bounds, bufH, fw1, fb1, fw2, fb2, out);
}

// Round 16
// 298.703 us; speedup vs baseline: 1.3564x; 1.0116x over previous
//
#include <hip/hip_runtime.h>
#include <hip/hip_bf16.h>
#include <math.h>

#define N_NODES 100000
#define N_EDGES 1600000
#define F_IN 256
#define H_DIM 128
#define N_GRAPHS 1000

#define NB_BUCKETS ((N_NODES + 255) >> 8)   // 391 buckets of 256 nodes
#define BSTRIDE 392
#define A_BLOCKS 256
#define EPB (N_EDGES / A_BLOCKS)            // 6250 edges per block (exact)

typedef unsigned short bfu;  // bf16 bit pattern
typedef unsigned char u8;
typedef short short8 __attribute__((ext_vector_type(8)));   // 8 bf16 = 4 VGPR
typedef float f32x4 __attribute__((ext_vector_type(4)));    // MFMA accum
typedef float f32x2 __attribute__((ext_vector_type(2)));

__device__ __forceinline__ float b2f(unsigned u) {
    union { unsigned int i; float f; } v;
    v.i = u << 16;
    return v.f;
}
__device__ __forceinline__ bfu f2b(float f) {
    __hip_bfloat16 h = __float2bfloat16(f);  // RNE
    return *reinterpret_cast<bfu*>(&h);
}
// 4 f32 -> 4 fp8(e4m3) bytes packed in a dword (HW cvt, RNE+sat)
__device__ __forceinline__ unsigned pk4_fp8(float v0, float v1, float v2, float v3) {
    int r = __builtin_amdgcn_cvt_pk_fp8_f32(v0, v1, 0, false);
    r = __builtin_amdgcn_cvt_pk_fp8_f32(v2, v3, r, true);
    return (unsigned)r;
}
// accumulate 4 fp8 (one dword) into a[0..3]
__device__ __forceinline__ void acc4_fp8(float* a, unsigned v) {
    f32x2 p;
    p = __builtin_amdgcn_cvt_pk_f32_fp8((int)v, false); a[0] += p.x; a[1] += p.y;
    p = __builtin_amdgcn_cvt_pk_f32_fp8((int)v, true);  a[2] += p.x; a[3] += p.y;
}
// 8 fp8 (uint2) -> 8 bf16 (uint4), exact (e4m3 subset of bf16)
__device__ __forceinline__ uint4 fp8x8_to_bf16x8(uint2 v) {
    f32x2 p0 = __builtin_amdgcn_cvt_pk_f32_fp8((int)v.x, false);
    f32x2 p1 = __builtin_amdgcn_cvt_pk_f32_fp8((int)v.x, true);
    f32x2 p2 = __builtin_amdgcn_cvt_pk_f32_fp8((int)v.y, false);
    f32x2 p3 = __builtin_amdgcn_cvt_pk_f32_fp8((int)v.y, true);
    uint4 o;
    o.x = (unsigned)f2b(p0.x) | ((unsigned)f2b(p0.y) << 16);
    o.y = (unsigned)f2b(p1.x) | ((unsigned)f2b(p1.y) << 16);
    o.z = (unsigned)f2b(p2.x) | ((unsigned)f2b(p2.y) << 16);
    o.w = (unsigned)f2b(p3.x) | ((unsigned)f2b(p3.y) << 16);
    return o;
}
// async global->LDS, 16 B per lane; lds base must be wave-uniform (HW adds lane*16)
__device__ __forceinline__ void gl_lds16(const void* g, void* lds) {
    __builtin_amdgcn_global_load_lds(
        (const __attribute__((address_space(1))) unsigned int*)g,
        (__attribute__((address_space(3))) unsigned int*)lds, 16, 0, 0);
}

// ---------------- CSR build: bucketed counting sort ----------------
__global__ __launch_bounds__(256) void k_hist(const int* __restrict__ dst,
                                              int* __restrict__ cnt_bb) {
    __shared__ int h[BSTRIDE];
    const int t = threadIdx.x;
    for (int i = t; i < BSTRIDE; i += 256) h[i] = 0;
    __syncthreads();
    const int base = blockIdx.x * EPB;
    for (int i = t; i < EPB; i += 256) atomicAdd(&h[dst[base + i] >> 8], 1);
    __syncthreads();
    for (int i = t; i < NB_BUCKETS; i += 256) cnt_bb[blockIdx.x * BSTRIDE + i] = h[i];
}

__global__ __launch_bounds__(256) void k_scan_blocks(int* __restrict__ cnt_bb,
                                                     int* __restrict__ btot) {
    __shared__ int s[256];
    const int t = threadIdx.x;
    const int b = blockIdx.x;
    int v = cnt_bb[t * BSTRIDE + b];
    s[t] = v;
    __syncthreads();
    for (int off = 1; off < 256; off <<= 1) {
        int u = (t >= off) ? s[t - off] : 0;
        __syncthreads();
        s[t] += u;
        __syncthreads();
    }
    cnt_bb[t * BSTRIDE + b] = s[t] - v;
    if (t == 255) btot[b] = s[255];
}

__global__ __launch_bounds__(256) void k_stage(const int* __restrict__ src,
                                               const int* __restrict__ dst,
                                               const int* __restrict__ cnt_bb,
                                               const int* __restrict__ bucket_base,
                                               unsigned* __restrict__ staging) {
    __shared__ int cur[BSTRIDE];
    const int t = threadIdx.x;
    const int blk = blockIdx.x;
    for (int i = t; i < NB_BUCKETS; i += 256)
        cur[i] = bucket_base[i] + cnt_bb[blk * BSTRIDE + i];
    __syncthreads();
    const int base = blk * EPB;
    for (int i = t; i < EPB; i += 256) {
        int d = dst[base + i];
        int s = src[base + i];
        int b = d >> 8;
        int pos = atomicAdd(&cur[b], 1);
        staging[pos] = (unsigned)s | ((unsigned)(d & 255) << 24);
    }
}

__global__ __launch_bounds__(256) void k_bucket(const unsigned* __restrict__ staging,
                                                const int* __restrict__ bucket_base,
                                                int* __restrict__ row_ptr,
                                                float* __restrict__ dis,
                                                int* __restrict__ col) {
    __shared__ int h[256];
    __shared__ int sc[256];
    __shared__ int cur[256];
    const int t = threadIdx.x;
    const int b = blockIdx.x;
    const int s0 = bucket_base[b];
    const int ne = bucket_base[b + 1] - s0;
    h[t] = 0;
    __syncthreads();
    for (int i = t; i < ne; i += 256) atomicAdd(&h[staging[s0 + i] >> 24], 1);
    __syncthreads();
    int myc = h[t];
    sc[t] = myc;
    __syncthreads();
    for (int off = 1; off < 256; off <<= 1) {
        int u = (t >= off) ? sc[t - off] : 0;
        __syncthreads();
        sc[t] += u;
        __syncthreads();
    }
    int excl = sc[t] - myc;
    int node = b * 256 + t;
    if (node <= N_NODES) row_ptr[node] = s0 + excl;
    if (node < N_NODES) dis[node] = rsqrtf((float)(myc + 1));
    cur[t] = s0 + excl;
    __syncthreads();
    for (int i = t; i < ne; i += 256) {
        unsigned u = staging[s0 + i];
        int pos = atomicAdd(&cur[u >> 24], 1);
        col[pos] = (int)(u & 0xFFFFFFu);
    }
}

// ---------------- merged: W pre-packs + graph bounds + bucket scan (one launch) ----------------
__device__ __forceinline__ void wpack_one(const float* __restrict__ W,
                                          bfu* __restrict__ Wp, int u) {
    int lane = u & 63;
    int nf = (u >> 6) & 7;
    int ks = u >> 9;
    int k = ks * 32 + (lane >> 4) * 8;
    int n = nf * 16 + (lane & 15);
    bfu o[8];
#pragma unroll
    for (int j = 0; j < 8; ++j) o[j] = f2b(W[(k + j) * 128 + n]);
    uint4 pk;
    pk.x = (unsigned)o[0] | ((unsigned)o[1] << 16);
    pk.y = (unsigned)o[2] | ((unsigned)o[3] << 16);
    pk.z = (unsigned)o[4] | ((unsigned)o[5] << 16);
    pk.w = (unsigned)o[6] | ((unsigned)o[7] << 16);
    *(uint4*)&Wp[u * 8] = pk;
}

__global__ __launch_bounds__(256) void k_misc(const float* __restrict__ W1,
                                              const float* __restrict__ W2,
                                              const float* __restrict__ W3,
                                              bfu* __restrict__ wp1, bfu* __restrict__ wp2,
                                              bfu* __restrict__ wp3,
                                              const int* __restrict__ batch,
                                              int* __restrict__ bounds,
                                              const int* __restrict__ btot,
                                              int* __restrict__ bucket_base) {
    const int b = blockIdx.x, t = threadIdx.x;
    if (b < 16) {
        wpack_one(W1, wp1, b * 256 + t);
    } else if (b < 24) {
        wpack_one(W2, wp2, (b - 16) * 256 + t);
    } else if (b < 32) {
        wpack_one(W3, wp3, (b - 24) * 256 + t);
    } else if (b < 36) {
        int g = (b - 32) * 256 + t;
        if (g <= N_GRAPHS) {
            int lo = 0, hi = N_NODES;
            while (lo < hi) {
                int mid = (lo + hi) >> 1;
                if (batch[mid] < g) lo = mid + 1; else hi = mid;
            }
            bounds[g] = lo;
        }
    } else {
        __shared__ int s[256];
        int g0 = 2 * t, g1 = 2 * t + 1;
        int v0 = (g0 < NB_BUCKETS) ? btot[g0] : 0;
        int v1 = (g1 < NB_BUCKETS) ? btot[g1] : 0;
        int pair = v0 + v1;
        s[t] = pair;
        __syncthreads();
        for (int off = 1; off < 256; off <<= 1) {
            int u = (t >= off) ? s[t - off] : 0;
            __syncthreads();
            s[t] += u;
            __syncthreads();
        }
        int excl = s[t] - pair;
        if (g0 < NB_BUCKETS) bucket_base[g0] = excl;
        if (g1 < NB_BUCKETS) bucket_base[g1] = excl + v0;
        if (t == 0) bucket_base[NB_BUCKETS] = N_EDGES;
    }
}

// ---------------- mm1 v5: async global_load_lds staging (dbuf, swizzled source) ----------------
// 256 thr = 4 waves; 64-row tile, K=256 in 8 steps of 32 floats.
// LDS slab = 64 rows x 32 f32 (8 KB), LINEAR dest; per-lane GLOBAL address carries the
// XOR swizzle (chunk ^= row&7) so ds_read_b128 on the read side is ~2-way-conflict only.
__global__ __launch_bounds__(256) void k_mm1(const float* __restrict__ A,
                                             const bfu* __restrict__ Wp,
                                             const float* __restrict__ dis,
                                             u8* __restrict__ C8, int M) {
    __shared__ float Xs[2][2048];  // 2 x 8 KB
    const int t = threadIdx.x;
    const int w = t >> 6, l = t & 63, l15 = l & 15, lhi = l >> 4;
    const int row0 = blockIdx.x * 64;

    // chunk c in {0,1}: linear 16B-chunk index i = (c*4+w)*64 + l; row = i>>3; schunk = i&7
    // logical float offset of that chunk within the step slice = (schunk ^ (row&7))*4
    const int i0 = w * 64 + l;
    const int i1 = 256 + w * 64 + l;
    const int r0 = i0 >> 3, fo0 = ((i0 & 7) ^ (r0 & 7)) * 4;
    const int r1 = i1 >> 3, fo1 = ((i1 & 7) ^ (r1 & 7)) * 4;
    const float* g0 = A + (long)((row0 + r0) < M ? (row0 + r0) : 0) * 256 + fo0;
    const float* g1 = A + (long)((row0 + r1) < M ? (row0 + r1) : 0) * 256 + fo1;

    f32x4 acc[8];
#pragma unroll
    for (int nf = 0; nf < 8; ++nf) acc[nf] = (f32x4)0.0f;

    // prologue: stage ks=0 into buf 0 (lds base wave-uniform: chunk (c*4+w)*64 -> float offset *4)
    gl_lds16(g0, &Xs[0][w * 256]);
    gl_lds16(g1, &Xs[0][1024 + w * 256]);

    int buf = 0;
    const int rr = w * 16 + l15;
    const int ca = (lhi * 2) ^ (rr & 7);
    const int cb = (lhi * 2 + 1) ^ (rr & 7);
#pragma unroll
    for (int ks = 0; ks < 8; ++ks) {
        __syncthreads();  // stage(ks) complete (implicit vmcnt drain)
        if (ks + 1 < 8) {  // issue stage(ks+1) now; latency hides under MFMA below
            gl_lds16(g0 + (ks + 1) * 32, &Xs[buf ^ 1][w * 256]);
            gl_lds16(g1 + (ks + 1) * 32, &Xs[buf ^ 1][1024 + w * 256]);
        }
        float4 fa = *(const float4*)&Xs[buf][rr * 32 + ca * 4];
        float4 fb = *(const float4*)&Xs[buf][rr * 32 + cb * 4];
        unsigned p0 = (unsigned)f2b(fa.x) | ((unsigned)f2b(fa.y) << 16);
        unsigned p1 = (unsigned)f2b(fa.z) | ((unsigned)f2b(fa.w) << 16);
        unsigned p2 = (unsigned)f2b(fb.x) | ((unsigned)f2b(fb.y) << 16);
        unsigned p3 = (unsigned)f2b(fb.z) | ((unsigned)f2b(fb.w) << 16);
        uint4 afu = make_uint4(p0, p1, p2, p3);
        short8 af = *(short8*)&afu;
        const bfu* wp = Wp + ((long)(ks * 8) * 64 + l) * 8;
#pragma unroll
        for (int nf = 0; nf < 8; ++nf) {
            short8 wf = *(const short8*)(wp + (long)nf * 64 * 8);
            acc[nf] = __builtin_amdgcn_mfma_f32_16x16x32_bf16(wf, af, acc[nf], 0, 0, 0);
        }
        __syncthreads();  // all waves done reading buf before it is restaged
        buf ^= 1;
    }

    int row = row0 + rr;
    if (row < M) {
        float sc = dis[row];
        int nb0 = lhi * 4;
#pragma unroll
        for (int nf = 0; nf < 8; ++nf) {
            unsigned pk = pk4_fp8(acc[nf][0] * sc, acc[nf][1] * sc,
                                  acc[nf][2] * sc, acc[nf][3] * sc);
            *(unsigned*)&C8[(long)row * 128 + nf * 16 + nb0] = pk;
        }
    }
}

// ---------------- agg8: fp8 t' gather -> h (fp8 for layers 1/2, bf16 for layer 3) ----------------
template <bool OUT_BF16>
__global__ __launch_bounds__(256) void k_agg8(const int* __restrict__ row_ptr,
                                              const int* __restrict__ col,
                                              const float* __restrict__ dis,
                                              const u8* __restrict__ t8,
                                              const float* __restrict__ b,
                                              bfu* __restrict__ h16,
                                              u8* __restrict__ h8) {
    const int t = threadIdx.x;
    const int node = blockIdx.x * 8 + (t >> 5);
    const int lane = t & 31;
    if (node >= N_NODES) return;
    const int q = lane << 2;  // 4 channels per lane (4 fp8 bytes)

    const u8* tp = t8 + q;
    float a[4] = {0.f, 0.f, 0.f, 0.f};
    acc4_fp8(a, *(const unsigned*)&tp[(long)node * 128]);  // self term

    int e = row_ptr[node];
    const int end = row_ptr[node + 1];
    for (; e + 7 < end; e += 8) {
        unsigned v[8];
#pragma unroll
        for (int j = 0; j < 8; ++j) v[j] = *(const unsigned*)&tp[(long)col[e + j] * 128];
#pragma unroll
        for (int j = 0; j < 8; ++j) acc4_fp8(a, v[j]);
    }
    for (; e + 3 < end; e += 4) {
        unsigned v0 = *(const unsigned*)&tp[(long)col[e] * 128];
        unsigned v1 = *(const unsigned*)&tp[(long)col[e + 1] * 128];
        unsigned v2 = *(const unsigned*)&tp[(long)col[e + 2] * 128];
        unsigned v3 = *(const unsigned*)&tp[(long)col[e + 3] * 128];
        acc4_fp8(a, v0); acc4_fp8(a, v1); acc4_fp8(a, v2); acc4_fp8(a, v3);
    }
    for (; e < end; ++e)
        acc4_fp8(a, *(const unsigned*)&tp[(long)col[e] * 128]);

    const float dn = dis[node];
    float4 bb = *(const float4*)&b[q];
    float o0 = fmaxf(a[0] * dn + bb.x, 0.0f);
    float o1 = fmaxf(a[1] * dn + bb.y, 0.0f);
    float o2 = fmaxf(a[2] * dn + bb.z, 0.0f);
    float o3 = fmaxf(a[3] * dn + bb.w, 0.0f);
    if (OUT_BF16) {
        uint2 pk;
        pk.x = (unsigned)f2b(o0) | ((unsigned)f2b(o1) << 16);
        pk.y = (unsigned)f2b(o2) | ((unsigned)f2b(o3) << 16);
        *(uint2*)&h16[(long)node * 128 + q] = pk;
    } else {
        *(unsigned*)&h8[(long)node * 128 + q] = pk4_fp8(o0, o1, o2, o3);
    }
}

// ---------------- mm2: fp8 h (streaming) @ W -> fp8 t' (dbuf LDS + reg prefetch) ----------------
__global__ __launch_bounds__(256) void k_mm2(const u8* __restrict__ A8,
                                             const bfu* __restrict__ Wp,
                                             const float* __restrict__ dis,
                                             u8* __restrict__ C8, int M) {
    __shared__ bfu As[2][64 * 40];
    const int t = threadIdx.x;
    const int w = t >> 6;
    const int l = t & 63;
    const int l15 = l & 15;
    const int lhi = l >> 4;
    const int row0 = blockIdx.x * 64;

    f32x4 acc[8];
#pragma unroll
    for (int nf = 0; nf < 8; ++nf) acc[nf] = (f32x4)0.0f;

    uint2 pb = make_uint2(0u, 0u);
    {
        int r = t >> 2, s = t & 3;
        if (row0 + r < M) pb = *(const uint2*)&A8[(long)(row0 + r) * 128 + s * 8];
    }

    int buf = 0;
#pragma unroll
    for (int ks = 0; ks < 4; ++ks) {
        *(uint4*)&As[buf][(t >> 2) * 40 + (t & 3) * 8] = fp8x8_to_bf16x8(pb);
        if (ks + 1 < 4) {
            const int k0n = (ks + 1) * 32;
            int r = t >> 2, s = t & 3;
            pb = make_uint2(0u, 0u);
            if (row0 + r < M) pb = *(const uint2*)&A8[(long)(row0 + r) * 128 + k0n + s * 8];
        }
        __syncthreads();
        short8 af = *(const short8*)&As[buf][(w * 16 + l15) * 40 + lhi * 8];
        const bfu* wp = Wp + ((long)(ks * 8) * 64 + l) * 8;
#pragma unroll
        for (int nf = 0; nf < 8; ++nf) {
            short8 wf = *(const short8*)(wp + (long)nf * 64 * 8);
            acc[nf] = __builtin_amdgcn_mfma_f32_16x16x32_bf16(wf, af, acc[nf], 0, 0, 0);
        }
        if (ks + 1 < 4) __syncthreads();
        buf ^= 1;
    }
    int row = row0 + w * 16 + l15;
    if (row < M) {
        float sc = dis[row];
        int nb0 = lhi * 4;
#pragma unroll
        for (int nf = 0; nf < 8; ++nf) {
            unsigned pko = pk4_fp8(acc[nf][0] * sc, acc[nf][1] * sc,
                                   acc[nf][2] * sc, acc[nf][3] * sc);
            *(unsigned*)&C8[(long)row * 128 + nf * 16 + nb0] = pko;
        }
    }
}

// ---------------- fused pool (mean over segment; h already relu'd) + MLP head ----------------
__global__ __launch_bounds__(128) void k_pool_head(const int* __restrict__ bounds,
                                                   const bfu* __restrict__ h,
                                                   const float* __restrict__ fw1, const float* __restrict__ fb1,
                                                   const float* __restrict__ fw2, const float* __restrict__ fb2,
                                                   float* __restrict__ out) {
    const int g = blockIdx.x;
    const int t = threadIdx.x;
    const int s = bounds[g], e = bounds[g + 1];
    float sum = 0.0f;
    int n = s;
    for (; n + 1 < e; n += 2) {
        sum += b2f(h[(long)n * 128 + t]);
        sum += b2f(h[(long)(n + 1) * 128 + t]);
    }
    if (n < e) sum += b2f(h[(long)n * 128 + t]);

    __shared__ float sg[128];
    __shared__ float sh[32];
    float inv = 1.0f / fmaxf((float)(e - s), 1.0f);
    sg[t] = sum * inv;
    __syncthreads();
    if (t < 32) {
        float a = fb1[t];
#pragma unroll 8
        for (int k = 0; k < 128; ++k) a += sg[k] * fw1[k * 32 + t];
        sh[t] = fmaxf(a, 0.0f);
    }
    __syncthreads();
    if (t == 0) {
        float l0 = fb2[0], l1 = fb2[1];
        for (int k = 0; k < 32; ++k) {
            l0 += sh[k] * fw2[k * 2];
            l1 += sh[k] * fw2[k * 2 + 1];
        }
        float m = fmaxf(l0, l1);
        float lse = m + logf(expf(l0 - m) + expf(l1 - m));
        out[g * 2 + 0] = l0 - lse;
        out[g * 2 + 1] = l1 - lse;
    }
}

extern "C" void kernel_launch(void* const* d_in, const int* in_sizes, int n_in,
                              void* d_out, int out_size, void* d_ws, size_t ws_size,
                              hipStream_t stream) {
    const float* x  = (const float*)d_in[0];
    const int* ei   = (const int*)d_in[1];
    const int* batch = (const int*)d_in[2];
    const float* W1 = (const float*)d_in[3];
    const float* b1 = (const float*)d_in[4];
    const float* W2 = (const float*)d_in[5];
    const float* b2 = (const float*)d_in[6];
    const float* W3 = (const float*)d_in[7];
    const float* b3 = (const float*)d_in[8];
    const float* fw1 = (const float*)d_in[9];
    const float* fb1 = (const float*)d_in[10];
    const float* fw2 = (const float*)d_in[11];
    const float* fb2 = (const float*)d_in[12];
    float* out = (float*)d_out;

    const int* src = ei;
    const int* dst = ei + N_EDGES;

    // workspace layout (all chunks multiple of 16 B)
    char* ws = (char*)d_ws;
    int*      cnt_bb      = (int*)ws;                            // 256*392
    int*      btot        = cnt_bb + A_BLOCKS * BSTRIDE;         // 392
    int*      bucket_base = btot + BSTRIDE;                      // 392+8
    unsigned* staging     = (unsigned*)(bucket_base + BSTRIDE + 8);  // E
    int*      row_ptr     = (int*)(staging + N_EDGES);           // N+4
    float*    dis         = (float*)(row_ptr + N_NODES + 4);     // N
    int*      col         = (int*)(dis + N_NODES);               // E
    int*      bounds      = col + N_EDGES;                       // G+1 (+pad)
    bfu*      wpack1      = (bfu*)(bounds + N_GRAPHS + 8);       // 32768 bfu (K=256)
    bfu*      wpack2      = wpack1 + 32768;                      // 16384 bfu (K=128)
    bfu*      wpack3      = wpack2 + 16384;                      // 16384 bfu
    u8*       bufT8       = (u8*)(wpack3 + 16384);               // N*128 fp8 (t1/t2/t3)
    u8*       bufH8       = bufT8 + (long)N_NODES * 128;         // N*128 fp8 (h1/h2)
    bfu*      bufH        = (bfu*)(bufH8 + (long)N_NODES * 128); // N*128 bf16 (h3)

    // ---- CSR build (counting sort) + merged wpack/bounds/bucket-scan ----
    k_hist<<<A_BLOCKS, 256, 0, stream>>>(dst, cnt_bb);
    k_scan_blocks<<<NB_BUCKETS, 256, 0, stream>>>(cnt_bb, btot);
    k_misc<<<37, 256, 0, stream>>>(W1, W2, W3, wpack1, wpack2, wpack3, batch, bounds,
                                   btot, bucket_base);
    k_stage<<<A_BLOCKS, 256, 0, stream>>>(src, dst, cnt_bb, bucket_base, staging);
    k_bucket<<<NB_BUCKETS, 256, 0, stream>>>(staging, bucket_base, row_ptr, dis, col);

    const int mm1Grid = (N_NODES + 63) / 64;      // 1563
    const int mm2Grid = (N_NODES + 63) / 64;      // 1563
    const int aggGrid = (N_NODES + 7) / 8;        // 12500

    // layer 1: t1(fp8) = (x @ W1) * dis ; h1(fp8) = relu(dis*gather(t1)+b1)
    k_mm1<<<mm1Grid, 256, 0, stream>>>(x, wpack1, dis, bufT8, N_NODES);
    k_agg8<false><<<aggGrid, 256, 0, stream>>>(row_ptr, col, dis, bufT8, b1, nullptr, bufH8);
    // layer 2: t2(fp8) = (h1 @ W2) * dis ; h2(fp8) = relu(dis*gather(t2)+b2)
    k_mm2<<<mm2Grid, 256, 0, stream>>>(bufH8, wpack2, dis, bufT8, N_NODES);
    k_agg8<false><<<aggGrid, 256, 0, stream>>>(row_ptr, col, dis, bufT8, b2, nullptr, bufH8);
    // layer 3: t3(fp8) = (h2 @ W3) * dis ; h3(bf16) = relu(dis*gather(t3)+b3)
    k_mm2<<<mm2Grid, 256, 0, stream>>>(bufH8, wpack3, dis, bufT8, N_NODES);
    k_agg8<true><<<aggGrid, 256, 0, stream>>>(row_ptr, col, dis, bufT8, b3, bufH, nullptr);

    // fused pool + head
    k_pool_head<<<N_GRAPHS, 128, 0, stream>>>(bounds, bufH, fw1, fb1, fw2, fb2, out);
}

// Round 17
// 294.281 us; speedup vs baseline: 1.3768x; 1.0150x over previous
//
#include <hip/hip_runtime.h>
#include <hip/hip_bf16.h>
#include <math.h>

#define N_NODES 100000
#define N_EDGES 1600000
#define F_IN 256
#define H_DIM 128
#define N_GRAPHS 1000

#define NB_BUCKETS ((N_NODES + 255) >> 8)   // 391 buckets of 256 nodes
#define BSTRIDE 392
#define A_BLOCKS 256
#define EPB (N_EDGES / A_BLOCKS)            // 6250 edges per block (exact)

typedef unsigned short bfu;  // bf16 bit pattern
typedef unsigned char u8;
typedef short short8 __attribute__((ext_vector_type(8)));   // 8 bf16 = 4 VGPR
typedef float f32x4 __attribute__((ext_vector_type(4)));    // MFMA accum
typedef float f32x2 __attribute__((ext_vector_type(2)));

__device__ __forceinline__ float b2f(unsigned u) {
    union { unsigned int i; float f; } v;
    v.i = u << 16;
    return v.f;
}
__device__ __forceinline__ bfu f2b(float f) {
    __hip_bfloat16 h = __float2bfloat16(f);  // RNE
    return *reinterpret_cast<bfu*>(&h);
}
// 4 f32 -> 4 fp8(e4m3) bytes packed in a dword (HW cvt, RNE+sat)
__device__ __forceinline__ unsigned pk4_fp8(float v0, float v1, float v2, float v3) {
    int r = __builtin_amdgcn_cvt_pk_fp8_f32(v0, v1, 0, false);
    r = __builtin_amdgcn_cvt_pk_fp8_f32(v2, v3, r, true);
    return (unsigned)r;
}
// accumulate 4 fp8 (one dword) into a[0..3]
__device__ __forceinline__ void acc4_fp8(float* a, unsigned v) {
    f32x2 p;
    p = __builtin_amdgcn_cvt_pk_f32_fp8((int)v, false); a[0] += p.x; a[1] += p.y;
    p = __builtin_amdgcn_cvt_pk_f32_fp8((int)v, true);  a[2] += p.x; a[3] += p.y;
}
// 8 fp8 (uint2) -> 8 bf16 (uint4), exact (e4m3 subset of bf16)
__device__ __forceinline__ uint4 fp8x8_to_bf16x8(uint2 v) {
    f32x2 p0 = __builtin_amdgcn_cvt_pk_f32_fp8((int)v.x, false);
    f32x2 p1 = __builtin_amdgcn_cvt_pk_f32_fp8((int)v.x, true);
    f32x2 p2 = __builtin_amdgcn_cvt_pk_f32_fp8((int)v.y, false);
    f32x2 p3 = __builtin_amdgcn_cvt_pk_f32_fp8((int)v.y, true);
    uint4 o;
    o.x = (unsigned)f2b(p0.x) | ((unsigned)f2b(p0.y) << 16);
    o.y = (unsigned)f2b(p1.x) | ((unsigned)f2b(p1.y) << 16);
    o.z = (unsigned)f2b(p2.x) | ((unsigned)f2b(p2.y) << 16);
    o.w = (unsigned)f2b(p3.x) | ((unsigned)f2b(p3.y) << 16);
    return o;
}
// async global->LDS, 16 B per lane; lds base wave-uniform (HW adds lane*16)
__device__ __forceinline__ void gl_lds16(const void* g, void* lds) {
    __builtin_amdgcn_global_load_lds(
        (const __attribute__((address_space(1))) unsigned int*)g,
        (__attribute__((address_space(3))) unsigned int*)lds, 16, 0, 0);
}

// ---------------- CSR build: bucketed counting sort ----------------
__global__ __launch_bounds__(256) void k_hist(const int* __restrict__ dst,
                                              int* __restrict__ cnt_bb) {
    __shared__ int h[BSTRIDE];
    const int t = threadIdx.x;
    for (int i = t; i < BSTRIDE; i += 256) h[i] = 0;
    __syncthreads();
    const int base = blockIdx.x * EPB;
    for (int i = t; i < EPB; i += 256) atomicAdd(&h[dst[base + i] >> 8], 1);
    __syncthreads();
    for (int i = t; i < NB_BUCKETS; i += 256) cnt_bb[blockIdx.x * BSTRIDE + i] = h[i];
}

__global__ __launch_bounds__(256) void k_scan_blocks(int* __restrict__ cnt_bb,
                                                     int* __restrict__ btot) {
    __shared__ int s[256];
    const int t = threadIdx.x;
    const int b = blockIdx.x;
    int v = cnt_bb[t * BSTRIDE + b];
    s[t] = v;
    __syncthreads();
    for (int off = 1; off < 256; off <<= 1) {
        int u = (t >= off) ? s[t - off] : 0;
        __syncthreads();
        s[t] += u;
        __syncthreads();
    }
    cnt_bb[t * BSTRIDE + b] = s[t] - v;
    if (t == 255) btot[b] = s[255];
}

__global__ __launch_bounds__(256) void k_stage(const int* __restrict__ src,
                                               const int* __restrict__ dst,
                                               const int* __restrict__ cnt_bb,
                                               const int* __restrict__ bucket_base,
                                               unsigned* __restrict__ staging) {
    __shared__ int cur[BSTRIDE];
    const int t = threadIdx.x;
    const int blk = blockIdx.x;
    for (int i = t; i < NB_BUCKETS; i += 256)
        cur[i] = bucket_base[i] + cnt_bb[blk * BSTRIDE + i];
    __syncthreads();
    const int base = blk * EPB;
    for (int i = t; i < EPB; i += 256) {
        int d = dst[base + i];
        int s = src[base + i];
        int b = d >> 8;
        int pos = atomicAdd(&cur[b], 1);
        staging[pos] = (unsigned)s | ((unsigned)(d & 255) << 24);
    }
}

__global__ __launch_bounds__(256) void k_bucket(const unsigned* __restrict__ staging,
                                                const int* __restrict__ bucket_base,
                                                int* __restrict__ row_ptr,
                                                float* __restrict__ dis,
                                                int* __restrict__ col) {
    __shared__ int h[256];
    __shared__ int sc[256];
    __shared__ int cur[256];
    const int t = threadIdx.x;
    const int b = blockIdx.x;
    const int s0 = bucket_base[b];
    const int ne = bucket_base[b + 1] - s0;
    h[t] = 0;
    __syncthreads();
    for (int i = t; i < ne; i += 256) atomicAdd(&h[staging[s0 + i] >> 24], 1);
    __syncthreads();
    int myc = h[t];
    sc[t] = myc;
    __syncthreads();
    for (int off = 1; off < 256; off <<= 1) {
        int u = (t >= off) ? sc[t - off] : 0;
        __syncthreads();
        sc[t] += u;
        __syncthreads();
    }
    int excl = sc[t] - myc;
    int node = b * 256 + t;
    if (node <= N_NODES) row_ptr[node] = s0 + excl;
    if (node < N_NODES) dis[node] = rsqrtf((float)(myc + 1));
    cur[t] = s0 + excl;
    __syncthreads();
    for (int i = t; i < ne; i += 256) {
        unsigned u = staging[s0 + i];
        int pos = atomicAdd(&cur[u >> 24], 1);
        col[pos] = (int)(u & 0xFFFFFFu);
    }
}

// ---------------- merged: W pre-packs + graph bounds + bucket scan (one launch) ----------------
__device__ __forceinline__ void wpack_one(const float* __restrict__ W,
                                          bfu* __restrict__ Wp, int u) {
    int lane = u & 63;
    int nf = (u >> 6) & 7;
    int ks = u >> 9;
    int k = ks * 32 + (lane >> 4) * 8;
    int n = nf * 16 + (lane & 15);
    bfu o[8];
#pragma unroll
    for (int j = 0; j < 8; ++j) o[j] = f2b(W[(k + j) * 128 + n]);
    uint4 pk;
    pk.x = (unsigned)o[0] | ((unsigned)o[1] << 16);
    pk.y = (unsigned)o[2] | ((unsigned)o[3] << 16);
    pk.z = (unsigned)o[4] | ((unsigned)o[5] << 16);
    pk.w = (unsigned)o[6] | ((unsigned)o[7] << 16);
    *(uint4*)&Wp[u * 8] = pk;
}

__global__ __launch_bounds__(256) void k_misc(const float* __restrict__ W1,
                                              const float* __restrict__ W2,
                                              const float* __restrict__ W3,
                                              bfu* __restrict__ wp1, bfu* __restrict__ wp2,
                                              bfu* __restrict__ wp3,
                                              const int* __restrict__ batch,
                                              int* __restrict__ bounds,
                                              const int* __restrict__ btot,
                                              int* __restrict__ bucket_base) {
    const int b = blockIdx.x, t = threadIdx.x;
    if (b < 16) {
        wpack_one(W1, wp1, b * 256 + t);
    } else if (b < 24) {
        wpack_one(W2, wp2, (b - 16) * 256 + t);
    } else if (b < 32) {
        wpack_one(W3, wp3, (b - 24) * 256 + t);
    } else if (b < 36) {
        int g = (b - 32) * 256 + t;
        if (g <= N_GRAPHS) {
            int lo = 0, hi = N_NODES;
            while (lo < hi) {
                int mid = (lo + hi) >> 1;
                if (batch[mid] < g) lo = mid + 1; else hi = mid;
            }
            bounds[g] = lo;
        }
    } else {
        __shared__ int s[256];
        int g0 = 2 * t, g1 = 2 * t + 1;
        int v0 = (g0 < NB_BUCKETS) ? btot[g0] : 0;
        int v1 = (g1 < NB_BUCKETS) ? btot[g1] : 0;
        int pair = v0 + v1;
        s[t] = pair;
        __syncthreads();
        for (int off = 1; off < 256; off <<= 1) {
            int u = (t >= off) ? s[t - off] : 0;
            __syncthreads();
            s[t] += u;
            __syncthreads();
        }
        int excl = s[t] - pair;
        if (g0 < NB_BUCKETS) bucket_base[g0] = excl;
        if (g1 < NB_BUCKETS) bucket_base[g1] = excl + v0;
        if (t == 0) bucket_base[NB_BUCKETS] = N_EDGES;
    }
}

// ---------------- mm1 v6: wave-private async pipeline, NO barriers ----------------
// Each wave owns 16 rows; stages its 2 KB K-slab into wave-private LDS dbuf via
// global_load_lds (src XOR-swizzled, LDS linear). Loop fully unrolled so buffer
// indices are constants -> compiler can emit counted vmcnt instead of a drain.
__global__ __launch_bounds__(256) void k_mm1(const float* __restrict__ A,
                                             const bfu* __restrict__ Wp,
                                             const float* __restrict__ dis,
                                             u8* __restrict__ C8, int M) {
    __shared__ float Xs[4][2][512];  // [wave][buf][16 rows x 32 f] = 16 KB total
    const int t = threadIdx.x;
    const int w = t >> 6, l = t & 63, l15 = l & 15, lhi = l >> 4;
    const int row0 = blockIdx.x * 64 + w * 16;  // this wave's first row

    // staging chunks: i0 = l, i1 = 64+l over the 128 16B-chunks of the wave slab.
    // row = i>>3, source chunk = (i&7) ^ (row&7)  (inverse swizzle on GLOBAL side)
    const int i0 = l, i1 = 64 + l;
    const int r0 = i0 >> 3, fo0 = ((i0 & 7) ^ (r0 & 7)) * 4;
    const int r1 = i1 >> 3, fo1 = ((i1 & 7) ^ (r1 & 7)) * 4;
    const int gr0 = (row0 + r0) < M ? (row0 + r0) : (M - 1);
    const int gr1 = (row0 + r1) < M ? (row0 + r1) : (M - 1);
    const float* g0 = A + (long)gr0 * 256 + fo0;
    const float* g1 = A + (long)gr1 * 256 + fo1;

    f32x4 acc[8];
#pragma unroll
    for (int nf = 0; nf < 8; ++nf) acc[nf] = (f32x4)0.0f;

    // prologue: stage ks=0 into buf 0
    gl_lds16(g0, &Xs[w][0][0]);
    gl_lds16(g1, &Xs[w][0][256]);

    // swizzled read chunks for this lane's fragment (row l15, k-slice lhi*8..lhi*8+8)
    const int ca = (lhi * 2) ^ (l15 & 7);
    const int cb = (lhi * 2 + 1) ^ (l15 & 7);

#pragma unroll
    for (int ks = 0; ks < 8; ++ks) {
        const int cur = ks & 1;
        if (ks + 1 < 8) {  // issue next stage first; its 2 loads stay in flight
            gl_lds16(g0 + (ks + 1) * 32, &Xs[w][cur ^ 1][0]);
            gl_lds16(g1 + (ks + 1) * 32, &Xs[w][cur ^ 1][256]);
        }
        float4 fa = *(const float4*)&Xs[w][cur][l15 * 32 + ca * 4];
        float4 fb = *(const float4*)&Xs[w][cur][l15 * 32 + cb * 4];
        unsigned p0 = (unsigned)f2b(fa.x) | ((unsigned)f2b(fa.y) << 16);
        unsigned p1 = (unsigned)f2b(fa.z) | ((unsigned)f2b(fa.w) << 16);
        unsigned p2 = (unsigned)f2b(fb.x) | ((unsigned)f2b(fb.y) << 16);
        unsigned p3 = (unsigned)f2b(fb.z) | ((unsigned)f2b(fb.w) << 16);
        uint4 afu = make_uint4(p0, p1, p2, p3);
        short8 af = *(short8*)&afu;
        const bfu* wp = Wp + ((long)(ks * 8) * 64 + l) * 8;
#pragma unroll
        for (int nf = 0; nf < 8; ++nf) {
            short8 wf = *(const short8*)(wp + (long)nf * 64 * 8);
            acc[nf] = __builtin_amdgcn_mfma_f32_16x16x32_bf16(wf, af, acc[nf], 0, 0, 0);
        }
    }

    int row = row0 + l15;
    if (row < M) {
        float sc = dis[row];
        int nb0 = lhi * 4;
#pragma unroll
        for (int nf = 0; nf < 8; ++nf) {
            unsigned pk = pk4_fp8(acc[nf][0] * sc, acc[nf][1] * sc,
                                  acc[nf][2] * sc, acc[nf][3] * sc);
            *(unsigned*)&C8[(long)row * 128 + nf * 16 + nb0] = pk;
        }
    }
}

// ---------------- agg8: fp8 t' gather -> h (fp8 for layers 1/2, bf16 for layer 3) ----------------
template <bool OUT_BF16>
__global__ __launch_bounds__(256) void k_agg8(const int* __restrict__ row_ptr,
                                              const int* __restrict__ col,
                                              const float* __restrict__ dis,
                                              const u8* __restrict__ t8,
                                              const float* __restrict__ b,
                                              bfu* __restrict__ h16,
                                              u8* __restrict__ h8) {
    const int t = threadIdx.x;
    const int node = blockIdx.x * 8 + (t >> 5);
    const int lane = t & 31;
    if (node >= N_NODES) return;
    const int q = lane << 2;  // 4 channels per lane (4 fp8 bytes)

    const u8* tp = t8 + q;
    float a[4] = {0.f, 0.f, 0.f, 0.f};
    acc4_fp8(a, *(const unsigned*)&tp[(long)node * 128]);  // self term

    int e = row_ptr[node];
    const int end = row_ptr[node + 1];
    for (; e + 7 < end; e += 8) {
        unsigned v[8];
#pragma unroll
        for (int j = 0; j < 8; ++j) v[j] = *(const unsigned*)&tp[(long)col[e + j] * 128];
#pragma unroll
        for (int j = 0; j < 8; ++j) acc4_fp8(a, v[j]);
    }
    for (; e + 3 < end; e += 4) {
        unsigned v0 = *(const unsigned*)&tp[(long)col[e] * 128];
        unsigned v1 = *(const unsigned*)&tp[(long)col[e + 1] * 128];
        unsigned v2 = *(const unsigned*)&tp[(long)col[e + 2] * 128];
        unsigned v3 = *(const unsigned*)&tp[(long)col[e + 3] * 128];
        acc4_fp8(a, v0); acc4_fp8(a, v1); acc4_fp8(a, v2); acc4_fp8(a, v3);
    }
    for (; e < end; ++e)
        acc4_fp8(a, *(const unsigned*)&tp[(long)col[e] * 128]);

    const float dn = dis[node];
    float4 bb = *(const float4*)&b[q];
    float o0 = fmaxf(a[0] * dn + bb.x, 0.0f);
    float o1 = fmaxf(a[1] * dn + bb.y, 0.0f);
    float o2 = fmaxf(a[2] * dn + bb.z, 0.0f);
    float o3 = fmaxf(a[3] * dn + bb.w, 0.0f);
    if (OUT_BF16) {
        uint2 pk;
        pk.x = (unsigned)f2b(o0) | ((unsigned)f2b(o1) << 16);
        pk.y = (unsigned)f2b(o2) | ((unsigned)f2b(o3) << 16);
        *(uint2*)&h16[(long)node * 128 + q] = pk;
    } else {
        *(unsigned*)&h8[(long)node * 128 + q] = pk4_fp8(o0, o1, o2, o3);
    }
}

// ---------------- mm2: fp8 h (streaming) @ W -> fp8 t' (dbuf LDS + reg prefetch) ----------------
__global__ __launch_bounds__(256) void k_mm2(const u8* __restrict__ A8,
                                             const bfu* __restrict__ Wp,
                                             const float* __restrict__ dis,
                                             u8* __restrict__ C8, int M) {
    __shared__ bfu As[2][64 * 40];
    const int t = threadIdx.x;
    const int w = t >> 6;
    const int l = t & 63;
    const int l15 = l & 15;
    const int lhi = l >> 4;
    const int row0 = blockIdx.x * 64;

    f32x4 acc[8];
#pragma unroll
    for (int nf = 0; nf < 8; ++nf) acc[nf] = (f32x4)0.0f;

    uint2 pb = make_uint2(0u, 0u);
    {
        int r = t >> 2, s = t & 3;
        if (row0 + r < M) pb = *(const uint2*)&A8[(long)(row0 + r) * 128 + s * 8];
    }

    int buf = 0;
#pragma unroll
    for (int ks = 0; ks < 4; ++ks) {
        *(uint4*)&As[buf][(t >> 2) * 40 + (t & 3) * 8] = fp8x8_to_bf16x8(pb);
        if (ks + 1 < 4) {
            const int k0n = (ks + 1) * 32;
            int r = t >> 2, s = t & 3;
            pb = make_uint2(0u, 0u);
            if (row0 + r < M) pb = *(const uint2*)&A8[(long)(row0 + r) * 128 + k0n + s * 8];
        }
        __syncthreads();
        short8 af = *(const short8*)&As[buf][(w * 16 + l15) * 40 + lhi * 8];
        const bfu* wp = Wp + ((long)(ks * 8) * 64 + l) * 8;
#pragma unroll
        for (int nf = 0; nf < 8; ++nf) {
            short8 wf = *(const short8*)(wp + (long)nf * 64 * 8);
            acc[nf] = __builtin_amdgcn_mfma_f32_16x16x32_bf16(wf, af, acc[nf], 0, 0, 0);
        }
        if (ks + 1 < 4) __syncthreads();
        buf ^= 1;
    }
    int row = row0 + w * 16 + l15;
    if (row < M) {
        float sc = dis[row];
        int nb0 = lhi * 4;
#pragma unroll
        for (int nf = 0; nf < 8; ++nf) {
            unsigned pko = pk4_fp8(acc[nf][0] * sc, acc[nf][1] * sc,
                                   acc[nf][2] * sc, acc[nf][3] * sc);
            *(unsigned*)&C8[(long)row * 128 + nf * 16 + nb0] = pko;
        }
    }
}

// ---------------- fused pool (mean over segment; h already relu'd) + MLP head ----------------
__global__ __launch_bounds__(128) void k_pool_head(const int* __restrict__ bounds,
                                                   const bfu* __restrict__ h,
                                                   const float* __restrict__ fw1, const float* __restrict__ fb1,
                                                   const float* __restrict__ fw2, const float* __restrict__ fb2,
                                                   float* __restrict__ out) {
    const int g = blockIdx.x;
    const int t = threadIdx.x;
    const int s = bounds[g], e = bounds[g + 1];
    float sum = 0.0f;
    int n = s;
    for (; n + 1 < e; n += 2) {
        sum += b2f(h[(long)n * 128 + t]);
        sum += b2f(h[(long)(n + 1) * 128 + t]);
    }
    if (n < e) sum += b2f(h[(long)n * 128 + t]);

    __shared__ float sg[128];
    __shared__ float sh[32];
    float inv = 1.0f / fmaxf((float)(e - s), 1.0f);
    sg[t] = sum * inv;
    __syncthreads();
    if (t < 32) {
        float a = fb1[t];
#pragma unroll 8
        for (int k = 0; k < 128; ++k) a += sg[k] * fw1[k * 32 + t];
        sh[t] = fmaxf(a, 0.0f);
    }
    __syncthreads();
    if (t == 0) {
        float l0 = fb2[0], l1 = fb2[1];
        for (int k = 0; k < 32; ++k) {
            l0 += sh[k] * fw2[k * 2];
            l1 += sh[k] * fw2[k * 2 + 1];
        }
        float m = fmaxf(l0, l1);
        float lse = m + logf(expf(l0 - m) + expf(l1 - m));
        out[g * 2 + 0] = l0 - lse;
        out[g * 2 + 1] = l1 - lse;
    }
}

extern "C" void kernel_launch(void* const* d_in, const int* in_sizes, int n_in,
                              void* d_out, int out_size, void* d_ws, size_t ws_size,
                              hipStream_t stream) {
    const float* x  = (const float*)d_in[0];
    const int* ei   = (const int*)d_in[1];
    const int* batch = (const int*)d_in[2];
    const float* W1 = (const float*)d_in[3];
    const float* b1 = (const float*)d_in[4];
    const float* W2 = (const float*)d_in[5];
    const float* b2 = (const float*)d_in[6];
    const float* W3 = (const float*)d_in[7];
    const float* b3 = (const float*)d_in[8];
    const float* fw1 = (const float*)d_in[9];
    const float* fb1 = (const float*)d_in[10];
    const float* fw2 = (const float*)d_in[11];
    const float* fb2 = (const float*)d_in[12];
    float* out = (float*)d_out;

    const int* src = ei;
    const int* dst = ei + N_EDGES;

    // workspace layout (all chunks multiple of 16 B)
    char* ws = (char*)d_ws;
    int*      cnt_bb      = (int*)ws;                            // 256*392
    int*      btot        = cnt_bb + A_BLOCKS * BSTRIDE;         // 392
    int*      bucket_base = btot + BSTRIDE;                      // 392+8
    unsigned* staging     = (unsigned*)(bucket_base + BSTRIDE + 8);  // E
    int*      row_ptr     = (int*)(staging + N_EDGES);           // N+4
    float*    dis         = (float*)(row_ptr + N_NODES + 4);     // N
    int*      col         = (int*)(dis + N_NODES);               // E
    int*      bounds      = col + N_EDGES;                       // G+1 (+pad)
    bfu*      wpack1      = (bfu*)(bounds + N_GRAPHS + 8);       // 32768 bfu (K=256)
    bfu*      wpack2      = wpack1 + 32768;                      // 16384 bfu (K=128)
    bfu*      wpack3      = wpack2 + 16384;                      // 16384 bfu
    u8*       bufT8       = (u8*)(wpack3 + 16384);               // N*128 fp8 (t1/t2/t3)
    u8*       bufH8       = bufT8 + (long)N_NODES * 128;         // N*128 fp8 (h1/h2)
    bfu*      bufH        = (bfu*)(bufH8 + (long)N_NODES * 128); // N*128 bf16 (h3)

    // ---- CSR build (counting sort) + merged wpack/bounds/bucket-scan ----
    k_hist<<<A_BLOCKS, 256, 0, stream>>>(dst, cnt_bb);
    k_scan_blocks<<<NB_BUCKETS, 256, 0, stream>>>(cnt_bb, btot);
    k_misc<<<37, 256, 0, stream>>>(W1, W2, W3, wpack1, wpack2, wpack3, batch, bounds,
                                   btot, bucket_base);
    k_stage<<<A_BLOCKS, 256, 0, stream>>>(src, dst, cnt_bb, bucket_base, staging);
    k_bucket<<<NB_BUCKETS, 256, 0, stream>>>(staging, bucket_base, row_ptr, dis, col);

    const int mm1Grid = (N_NODES + 63) / 64;      // 1563
    const int mm2Grid = (N_NODES + 63) / 64;      // 1563
    const int aggGrid = (N_NODES + 7) / 8;        // 12500

    // layer 1: t1(fp8) = (x @ W1) * dis ; h1(fp8) = relu(dis*gather(t1)+b1)
    k_mm1<<<mm1Grid, 256, 0, stream>>>(x, wpack1, dis, bufT8, N_NODES);
    k_agg8<false><<<aggGrid, 256, 0, stream>>>(row_ptr, col, dis, bufT8, b1, nullptr, bufH8);
    // layer 2: t2(fp8) = (h1 @ W2) * dis ; h2(fp8) = relu(dis*gather(t2)+b2)
    k_mm2<<<mm2Grid, 256, 0, stream>>>(bufH8, wpack2, dis, bufT8, N_NODES);
    k_agg8<false><<<aggGrid, 256, 0, stream>>>(row_ptr, col, dis, bufT8, b2, nullptr, bufH8);
    // layer 3: t3(fp8) = (h2 @ W3) * dis ; h3(bf16) = relu(dis*gather(t3)+b3)
    k_mm2<<<mm2Grid, 256, 0, stream>>>(bufH8, wpack3, dis, bufT8, N_NODES);
    k_agg8<true><<<aggGrid, 256, 0, stream>>>(row_ptr, col, dis, bufT8, b3, bufH, nullptr);

    // fused pool + head
    k_pool_head<<<N_GRAPHS, 128, 0, stream>>>(bounds, bufH, fw1, fb1, fw2, fb2, out);
}